// Round 9
// baseline (327.663 us; speedup 1.0000x reference)
//
#include <hip/hip_runtime.h>
#include <hip/hip_bf16.h>

#define NN 100000
#define NE 1600000
#define NG 512
#define CHW 25088      // u32 words, u8-packed counters for ALL 100000 keys (100.4KB LDS)
                       // = 98*256 exactly (pads keys 100000..100351 with zeros)
#define BPC 128        // blocks (edge slices)
#define ES 12500       // NE / BPC

// Feature-column permutation: mem position p holds logical col (p&7)*16+(p>>3).
// sortedSrc payload: src[0:17) | type[17:21) | rel[21:23).  Bits >=21 are rel-only:
// this payload is part of gather_gemm1's interface.
//
// gather_gemm1 is pinned at the compulsory random-fetch floor (FETCH ~= 8 XCD x hbf,
// ~2.27 TB/s across 4 structural variants R9-R12) — and must remain BYTE-IDENTICAL:
// R17 added a single `&3` to rel extraction -> VGPR 48->56 -> occupancy 48->39% ->
// 99.6->116us (+16%). Latency-bound kernel sits on a register/occupancy cliff.
//
// R20 (R19 base, 319.7): SINGLE-CHUNK CSR build. gfx950 allows >64KB LDS per
// workgroup (160KB/CU; 128KB plain-HIP kernels verified on this chip), so the
// u8 counter table for all 100K keys (100.4KB) fits in one LDS block:
//  - hist: ONE edge pass (was 2 chunk passes), no bounds checks
//  - place: ONE pass; partials 16.8->12.85MB
//  - 16 waves/CU unchanged (1024 thr, 1 block/CU); grid 128 on 128 CUs
// LESSONS: scattered global atomics over >4MB (per-XCD L2) cost ~30ns each
// (R13 place 106MB write-amp, R15 cntG +45us). Launch-count alone worth ~0.

typedef __attribute__((ext_vector_type(8))) short short8;
typedef __attribute__((ext_vector_type(4))) float float4v;

// ---------------------------------------------------------------- utilities

__device__ inline int lower_bound_dev(const int* __restrict__ a, int n, int v) {
    int lo = 0, hi = n;
    while (lo < hi) { int mid = (lo + hi) >> 1; if (a[mid] < v) lo = mid + 1; else hi = mid; }
    return lo;
}

__device__ inline unsigned short f2bf(float x) {
    unsigned u = __float_as_uint(x);
    unsigned r = (u + 0x7fffu + ((u >> 16) & 1u)) >> 16;   // RNE
    return (unsigned short)r;
}

// ---------------------------------------------------------------- fused prep: weights + node types + zero inits
// blocks [0,320): Bf1.  [320,368): B0f.  [368,624): g0 zero.  [624,1015): node_type.
// blocks 0-15 also zero bnSums/bnSums1.

__global__ void build_weights(const float* __restrict__ emb, const float* __restrict__ Wroot,
                              const float* __restrict__ Wrel, const float* __restrict__ x,
                              unsigned short* __restrict__ Bf, unsigned short* __restrict__ B0f,
                              int* __restrict__ ntype,
                              float* __restrict__ bnSums, float* __restrict__ bnSums1,
                              float* __restrict__ g0) {
    if (blockIdx.x < 8) bnSums[blockIdx.x * 256 + threadIdx.x] = 0.f;
    else if (blockIdx.x < 16) bnSums1[(blockIdx.x - 8) * 256 + threadIdx.x] = 0.f;
    if (blockIdx.x >= 624) {
        int i = (blockIdx.x - 624) * 256 + threadIdx.x;
        if (i < NN) {
            const float* row = x + (size_t)i * 13;
            int b = 0;
            #pragma unroll
            for (int t = 0; t < 13; ++t) if (row[t] > 0.5f) { b = t; }
            ntype[i] = b;
        }
        return;
    }
    int i = blockIdx.x * 256 + threadIdx.x;
    if (i < 81920) {
        // layer-1 fragments, k-side permuted: kcol = j*16 + ks*4 + quad
        int j = i & 7;
        int lane = (i >> 3) & 63;
        int t = (i >> 9) & 7;
        int ks = (i >> 12) & 3;
        int kc = i >> 14;
        int n = t * 16 + (lane & 15);
        int kcol = j * 16 + ks * 4 + (lane >> 4);
        float w;
        if (kc == 0) w = Wroot[16384 + (size_t)kcol * 128 + n];
        else {
            int r = kc - 1;
            w = Wrel[(((size_t)(4 + r) * 128) + kcol) * 128 + n];
        }
        Bf[i] = f2bf(w);
    } else if (i < 94208) {
        int i0 = i - 81920;          // [0, 12288)
        int j = i0 & 7;
        int lane = (i0 >> 3) & 63;
        int t = (i0 >> 9) & 7;
        int ks = i0 >> 12;
        int n = t * 16 + (lane & 15);
        int p = ks * 32 + (lane >> 4) * 8 + j;
        float val = 0.f;
        if (p < 32) {
            if (p < 13) {
                const float* er = emb + (size_t)p * 128;
                const float* wc = Wroot + n;
                float acc = 0.f;
                for (int k = 0; k < 128; ++k) acc += er[k] * wc[(size_t)k * 128];
                val = acc;
            }
        } else {
            int r = (p - 32) >> 4, tt = (p - 32) & 15;
            if (tt < 13) {
                const float* er = emb + (size_t)tt * 128;
                const float* wc = Wrel + ((size_t)r * 128) * 128 + n;
                float acc = 0.f;
                for (int k = 0; k < 128; ++k) acc += er[k] * wc[(size_t)k * 128];
                val = acc;
            }
        }
        B0f[i0] = f2bf(val);
    } else {
        int gz = i - 94208;          // [0, 65536)
        g0[gz] = 0.f;
    }
}

// ---------------------------------------------------------------- CSR build, key = dst (SINGLE pass)
// Also packs srcT = src | type<<17 | rel<<21.

__global__ __launch_bounds__(1024) void hist_kernel(const int* __restrict__ dst,
                                                    const int* __restrict__ src,
                                                    const int* __restrict__ et,
                                                    const int* __restrict__ ntype,
                                                    int* __restrict__ srcT,
                                                    unsigned* __restrict__ partials) {
    __shared__ unsigned h[CHW];    // 100.4KB — gfx950 allows >64KB/workgroup
    const int b = blockIdx.x;
    for (int i = threadIdx.x; i < CHW; i += 1024) h[i] = 0;
    __syncthreads();
    const int e0 = b * ES;
    const int e1 = e0 + ES;        // NE = BPC*ES exact
    for (int e = e0 + threadIdx.x; e < e1; e += 1024) {
        int k = dst[e];
        atomicAdd(&h[k >> 2], 1u << ((k & 3) << 3));
        int s = src[e];
        srcT[e] = s | (ntype[s] << 17) | (et[e] << 21);
    }
    __syncthreads();
    unsigned* out = partials + (size_t)b * CHW;
    for (int i = threadIdx.x; i < CHW; i += 1024) out[i] = h[i];
}

// fused hist_reduce + scan1: per-word 128-block reduction (rewriting partials with
// running prefixes) feeds the block-local scan directly from registers.
// Block b covers keys [b*1024, b*1024+1024) = words [b*256, b*256+256); CHW = 98*256.
__global__ __launch_bounds__(256) void hr_scan1(unsigned* __restrict__ partials,
                                                int* __restrict__ offs,
                                                int* __restrict__ bsums, int n) {
    __shared__ int wsum[4];
    const int b = blockIdx.x;              // 0..97
    const int tid = threadIdx.x;
    const int i = b * 256 + tid;           // u32 word, < CHW always
    size_t base = (size_t)i;
    unsigned r0 = 0, r1 = 0, r2 = 0, r3 = 0;
    #pragma unroll 8
    for (int bb = 0; bb < BPC; ++bb) {
        unsigned t = partials[base + (size_t)bb * CHW];
        partials[base + (size_t)bb * CHW] = r0 | (r1 << 8) | (r2 << 16) | (r3 << 24);
        r0 += t & 0xffu; r1 += (t >> 8) & 0xffu; r2 += (t >> 16) & 0xffu; r3 += t >> 24;
    }
    int v[4] = {(int)r0, (int)r1, (int)r2, (int)r3};
    int loc = v[0] + v[1] + v[2] + v[3];
    const int lane = tid & 63, wid = tid >> 6;
    int sc = loc;
    #pragma unroll
    for (int o = 1; o < 64; o <<= 1) { int t = __shfl_up(sc, o, 64); if (lane >= o) sc += t; }
    if (lane == 63) wsum[wid] = sc;
    __syncthreads();
    int wbase = 0;
    for (int w = 0; w < wid; ++w) wbase += wsum[w];
    int run = wbase + sc - loc;
    const int key0 = b * 1024 + tid * 4;
    #pragma unroll
    for (int j = 0; j < 4; ++j) { int idx = key0 + j; if (idx < n) offs[idx] = run; run += v[j]; }
    if (tid == 255) bsums[b] = wbase + sc;
}

// merged scan2+scan3: each block redundantly prefix-reduces bsums (98 ints)
__global__ __launch_bounds__(256) void scan23(int* __restrict__ offs, const int* __restrict__ bsums,
                                              int nb, int n) {
    __shared__ int part[256];
    const int tid = threadIdx.x;
    int v = (tid < nb && tid < blockIdx.x) ? bsums[tid] : 0;
    part[tid] = v;
    __syncthreads();
    #pragma unroll
    for (int o = 128; o > 0; o >>= 1) {
        if (tid < o) part[tid] += part[tid + o];
        __syncthreads();
    }
    const int s = part[0];
    const int base = blockIdx.x * 1024 + tid * 4;
    #pragma unroll
    for (int j = 0; j < 4; ++j) { int idx = base + j; if (idx < n) offs[idx] += s; }
    if (blockIdx.x == (unsigned)(nb - 1) && tid == 0) offs[n] = s + bsums[nb - 1];
}

// placement: LDS u8 cursors over all keys; payload = srcT (type+rel already packed)
__global__ __launch_bounds__(1024) void place_kernel(const int* __restrict__ dst,
                                                     const int* __restrict__ srcT,
                                                     const int* __restrict__ offs,
                                                     const unsigned* __restrict__ partials,
                                                     int* __restrict__ sortedSrc) {
    __shared__ unsigned cur[CHW];  // 100.4KB
    const int b = blockIdx.x;
    const unsigned* pb = partials + (size_t)b * CHW;
    for (int i = threadIdx.x; i < CHW; i += 1024) cur[i] = pb[i];
    __syncthreads();
    const int e0 = b * ES;
    const int e1 = e0 + ES;
    for (int e = e0 + threadIdx.x; e < e1; e += 1024) {
        int key = dst[e];
        int sh = (key & 3) << 3;
        unsigned old = atomicAdd(&cur[key >> 2], 1u << sh);
        int my = (int)((old >> sh) & 0xffu);
        int pos = offs[key] + my;
        sortedSrc[pos] = srcT[e];
    }
}

// ---------------------------------------------------------------- FUSED layer-0: histogram + GEMM (K=96)
// Phase 1: all 256 threads — 2 threads per node, each walking half the edge
// range into a private cnt row (integer-exact merge). Phase 2: MFMA GEMM.
// A0L layout: [C=ks*4+quad (12)][tile(8)][l16(16)] 16B units.
// cnt and sred OVERLAY the same LDS: cnt's last read is before the post-A0-build
// barrier; sred's first write is after it (all threads pass that barrier).

__global__ __launch_bounds__(256) void gemm0_fused(const int* __restrict__ sortedSrc,
                                                   const int* __restrict__ offs,
                                                   const int* __restrict__ ntype,
                                                   const unsigned short* __restrict__ B0f,
                                                   const float* __restrict__ bias,
                                                   unsigned short* __restrict__ Cb,
                                                   float* __restrict__ bnSums, int M) {
    __shared__ unsigned short A0L[12 * 128 * 8];   // 24.6 KB
    __shared__ unsigned cntRaw[256 * 13];          // 13.3 KB, reused as sred[2][4][128]
    const int tid = threadIdx.x;
    float* sredF = (float*)cntRaw;                 // [(l*4+w)*128 + c]

    {
        const int node = tid & 127;
        const int half = tid >> 7;
        const int n = blockIdx.x * 128 + node;
        #pragma unroll
        for (int t = 0; t < 13; ++t) cntRaw[tid * 13 + t] = 0;
        if (n < M) {
            const int o0 = offs[n], o1 = offs[n + 1];
            const int mid = (o0 + o1) >> 1;
            const int lo = half ? mid : o0;
            const int hi = half ? o1 : mid;
            for (int i = lo; i < hi; ++i) {
                int v = sortedSrc[i];
                int ty = (v >> 17) & 15, r = v >> 21;
                cntRaw[tid * 13 + ty] += 1u << (r << 3);
            }
        }
    }
    __syncthreads();

    if (tid < 128) {
        const int n = blockIdx.x * 128 + tid;
        const int tile = tid >> 4, l16 = tid & 15;
        if (n < M) {
            unsigned cw[13]; unsigned relc = 0;
            #pragma unroll
            for (int t = 0; t < 13; ++t) { cw[t] = cntRaw[tid * 13 + t] + cntRaw[(tid + 128) * 13 + t]; relc += cw[t]; }
            float inv[4];
            #pragma unroll
            for (int r = 0; r < 4; ++r) {
                unsigned c = (relc >> (r << 3)) & 0xffu;
                inv[r] = 1.0f / (float)(c > 0 ? c : 1);
            }
            const int myty = ntype[n];
            #pragma unroll
            for (int ks = 0; ks < 3; ++ks) {
                #pragma unroll
                for (int quad = 0; quad < 4; ++quad) {
                    unsigned short vals[8];
                    #pragma unroll
                    for (int j = 0; j < 8; ++j) {
                        int p = ks * 32 + quad * 8 + j;
                        float v;
                        if (p < 32) v = (p == myty) ? 1.0f : 0.0f;
                        else {
                            int r = (p - 32) >> 4, tt = (p - 32) & 15;
                            v = (tt < 13) ? (float)((cw[tt] >> (r << 3)) & 0xffu) * inv[r] : 0.0f;
                        }
                        vals[j] = f2bf(v);
                    }
                    const int C = ks * 4 + quad;
                    *(uint4*)(A0L + (C * 128 + tile * 16 + l16) * 8) = *(uint4*)vals;
                }
            }
        } else {
            uint4 z; z.x = 0; z.y = 0; z.z = 0; z.w = 0;
            #pragma unroll
            for (int C = 0; C < 12; ++C)
                *(uint4*)(A0L + (C * 128 + tile * 16 + l16) * 8) = z;
        }
    }
    __syncthreads();   // after this barrier cnt is dead; sredF may be written

    // ---- GEMM phase
    const int wv = tid >> 6, lane = tid & 63;
    const int l16 = lane & 15, quad = lane >> 4;
    const int rowbase = blockIdx.x * 128 + wv * 32;
    const int tileL0 = wv * 2, tileL1 = wv * 2 + 1;

    float4v acc[2][8];
    #pragma unroll
    for (int t = 0; t < 8; ++t) {
        float bv = bias[t * 16 + l16];
        float4v av = {bv, bv, bv, bv};
        acc[0][t] = av; acc[1][t] = av;
    }

    const unsigned short* bl = B0f + lane * 8;
    #pragma unroll
    for (int ks = 0; ks < 3; ++ks) {
        const int C = ks * 4 + quad;
        short8 af0 = *(const short8*)(A0L + (C * 128 + tileL0 * 16 + l16) * 8);
        short8 af1 = *(const short8*)(A0L + (C * 128 + tileL1 * 16 + l16) * 8);
        const unsigned short* bp = bl + ((ks * 8) << 9);
        #pragma unroll
        for (int t = 0; t < 8; ++t) {
            short8 bf = *(const short8*)(bp + (t << 9));
            acc[0][t] = __builtin_amdgcn_mfma_f32_16x16x32_bf16(af0, bf, acc[0][t], 0, 0, 0);
            acc[1][t] = __builtin_amdgcn_mfma_f32_16x16x32_bf16(af1, bf, acc[1][t], 0, 0, 0);
        }
    }

    #pragma unroll
    for (int h = 0; h < 2; ++h) {
        #pragma unroll
        for (int rg = 0; rg < 4; ++rg) {
            int rr = rowbase + h * 16 + quad * 4 + rg;
            if (rr < M) {
                unsigned short v[8];
                #pragma unroll
                for (int t = 0; t < 8; ++t) v[t] = f2bf(acc[h][t][rg]);
                *(uint4*)(Cb + (size_t)rr * 128 + l16 * 8) = *(uint4*)v;
            }
        }
    }
    float s[8], q[8];
    #pragma unroll
    for (int t = 0; t < 8; ++t) {
        s[t] = 0.f; q[t] = 0.f;
        #pragma unroll
        for (int h = 0; h < 2; ++h) {
            #pragma unroll
            for (int rg = 0; rg < 4; ++rg) {
                int rr = rowbase + h * 16 + quad * 4 + rg;
                if (rr < M) { float v = acc[h][t][rg]; s[t] += v; q[t] += v * v; }
            }
        }
    }
    #pragma unroll
    for (int t = 0; t < 8; ++t) {
        s[t] += __shfl_down(s[t], 32, 64); q[t] += __shfl_down(q[t], 32, 64);
        s[t] += __shfl_down(s[t], 16, 64); q[t] += __shfl_down(q[t], 16, 64);
    }
    if (lane < 16) {
        #pragma unroll
        for (int t = 0; t < 8; ++t) {
            sredF[wv * 128 + t * 16 + l16] = s[t];        // [0][wv]
            sredF[(4 + wv) * 128 + t * 16 + l16] = q[t];  // [1][wv]
        }
    }
    __syncthreads();
    if (tid < 128) {
        float S = sredF[0 * 128 + tid] + sredF[1 * 128 + tid] + sredF[2 * 128 + tid] + sredF[3 * 128 + tid];
        float Q = sredF[4 * 128 + tid] + sredF[5 * 128 + tid] + sredF[6 * 128 + tid] + sredF[7 * 128 + tid];
        float* bnS = bnSums + ((blockIdx.x & 7) << 8);
        unsafeAtomicAdd(bnS + tid, S);
        unsafeAtomicAdd(bnS + 128 + tid, Q);
    }
}

// ---------------------------------------------------------------- FUSED layer-1: gather + GEMM (BYTE-IDENTICAL — do not touch)

__global__ __launch_bounds__(256) void gather_gemm1(const unsigned short* __restrict__ hbf,
                                                    const int* __restrict__ sortedSrc,
                                                    const int* __restrict__ offs,
                                                    const unsigned short* __restrict__ Bf,
                                                    const float* __restrict__ bias,
                                                    unsigned short* __restrict__ Cb,
                                                    float* __restrict__ bnSums) {
    __shared__ unsigned short rootL[2048];   // 4KB  (16B-unit swizzled)
    __shared__ unsigned short aggL[8192];    // 16KB (4 rel blocks, swizzled)
    const int tid = threadIdx.x;
    const int tile = blockIdx.x;
    {
        const int l16g = tid >> 4;
        const int cidx = tid & 15;
        const int c8 = cidx << 3;
        const int n = tile * 16 + l16g;                  // NN = 6250*16 exact
        const int pu = cidx * 16 + (l16g ^ cidx);        // swizzled unit
        uint4 ru = *(const uint4*)(hbf + (size_t)n * 128 + c8);
        *(uint4*)(rootL + pu * 8) = ru;

        const unsigned short* hb = hbf + c8;
        const int o0 = offs[n], o1 = offs[n + 1];

        float a0[8], a1[8], a2[8], a3[8];
        #pragma unroll
        for (int j = 0; j < 8; ++j) { a0[j] = 0.f; a1[j] = 0.f; a2[j] = 0.f; a3[j] = 0.f; }
        float c0 = 0.f, c1 = 0.f, c2 = 0.f, c3 = 0.f;

        auto body = [&](int v, uint4 u) {
            int r = v >> 21;
            float f[8];
            f[0] = __uint_as_float(u.x << 16); f[1] = __uint_as_float(u.x & 0xffff0000u);
            f[2] = __uint_as_float(u.y << 16); f[3] = __uint_as_float(u.y & 0xffff0000u);
            f[4] = __uint_as_float(u.z << 16); f[5] = __uint_as_float(u.z & 0xffff0000u);
            f[6] = __uint_as_float(u.w << 16); f[7] = __uint_as_float(u.w & 0xffff0000u);
            float m0 = (r == 0) ? 1.f : 0.f, m1 = (r == 1) ? 1.f : 0.f;
            float m2 = (r == 2) ? 1.f : 0.f, m3 = (r == 3) ? 1.f : 0.f;
            c0 += m0; c1 += m1; c2 += m2; c3 += m3;
            #pragma unroll
            for (int j = 0; j < 8; ++j) {
                a0[j] = fmaf(m0, f[j], a0[j]);
                a1[j] = fmaf(m1, f[j], a1[j]);
                a2[j] = fmaf(m2, f[j], a2[j]);
                a3[j] = fmaf(m3, f[j], a3[j]);
            }
        };

        int i = o0;
        for (; i + 4 <= o1; i += 4) {
            int v0 = sortedSrc[i], v1 = sortedSrc[i + 1];
            int v2 = sortedSrc[i + 2], v3 = sortedSrc[i + 3];
            uint4 u0 = *(const uint4*)(hb + (size_t)(v0 & 0x1ffff) * 128);
            uint4 u1 = *(const uint4*)(hb + (size_t)(v1 & 0x1ffff) * 128);
            uint4 u2 = *(const uint4*)(hb + (size_t)(v2 & 0x1ffff) * 128);
            uint4 u3 = *(const uint4*)(hb + (size_t)(v3 & 0x1ffff) * 128);
            body(v0, u0); body(v1, u1); body(v2, u2); body(v3, u3);
        }
        if (i + 2 <= o1) {
            int v0 = sortedSrc[i], v1 = sortedSrc[i + 1];
            uint4 u0 = *(const uint4*)(hb + (size_t)(v0 & 0x1ffff) * 128);
            uint4 u1 = *(const uint4*)(hb + (size_t)(v1 & 0x1ffff) * 128);
            body(v0, u0); body(v1, u1);
            i += 2;
        }
        if (i < o1) {
            int v0 = sortedSrc[i];
            uint4 u0 = *(const uint4*)(hb + (size_t)(v0 & 0x1ffff) * 128);
            body(v0, u0);
        }

        const float i0 = 1.f / fmaxf(c0, 1.f), i1 = 1.f / fmaxf(c1, 1.f);
        const float i2 = 1.f / fmaxf(c2, 1.f), i3 = 1.f / fmaxf(c3, 1.f);
        unsigned short* bp = aggL + pu * 8;
        auto pack = [&](float* a, float inv, unsigned short* dp) {
            unsigned short v[8];
            #pragma unroll
            for (int j = 0; j < 8; ++j) v[j] = f2bf(a[j] * inv);
            *(uint4*)dp = *(uint4*)v;
        };
        pack(a0, i0, bp);
        pack(a1, i1, bp + 2048);
        pack(a2, i2, bp + 4096);
        pack(a3, i3, bp + 6144);
    }
    __syncthreads();

    // ---- GEMM phase: wave wv handles output cols t0=2wv, t0+1
    const int wv = tid >> 6, lane = tid & 63;
    const int l16 = lane & 15, quad = lane >> 4;
    const int t0 = wv << 1;
    float4v acc0, acc1;
    {
        float b0v = bias[t0 * 16 + l16];
        float b1v = bias[(t0 + 1) * 16 + l16];
        float4v a0v = {b0v, b0v, b0v, b0v};
        float4v a1v = {b1v, b1v, b1v, b1v};
        acc0 = a0v; acc1 = a1v;
    }
    const unsigned short* bl = Bf + lane * 8;
    #pragma unroll
    for (int kc = 0; kc < 5; ++kc) {
        const unsigned short* Abase = (kc == 0) ? rootL : (aggL + (kc - 1) * 2048);
        #pragma unroll
        for (int ks = 0; ks < 4; ++ks) {
            const int C = ks * 4 + quad;
            const int p = C * 16 + (l16 ^ C);
            short8 af = *(const short8*)(Abase + p * 8);
            const unsigned short* bp = bl + (((kc * 4 + ks) * 8 + t0) << 9);
            short8 b0 = *(const short8*)(bp);
            short8 b1 = *(const short8*)(bp + 512);
            acc0 = __builtin_amdgcn_mfma_f32_16x16x32_bf16(af, b0, acc0, 0, 0, 0);
            acc1 = __builtin_amdgcn_mfma_f32_16x16x32_bf16(af, b1, acc1, 0, 0, 0);
        }
    }
    const int rowbase = tile * 16;
    #pragma unroll
    for (int rg = 0; rg < 4; ++rg) {
        int rr = rowbase + quad * 4 + rg;
        unsigned pk = (unsigned)f2bf(acc0[rg]) | ((unsigned)f2bf(acc1[rg]) << 16);
        *(unsigned*)(Cb + (size_t)rr * 128 + l16 * 8 + t0) = pk;
    }
    float s0 = 0.f, q0 = 0.f, s1 = 0.f, q1 = 0.f;
    #pragma unroll
    for (int rg = 0; rg < 4; ++rg) {
        float v0 = acc0[rg], v1 = acc1[rg];
        s0 += v0; q0 += v0 * v0; s1 += v1; q1 += v1 * v1;
    }
    s0 += __shfl_down(s0, 32, 64); q0 += __shfl_down(q0, 32, 64);
    s1 += __shfl_down(s1, 32, 64); q1 += __shfl_down(q1, 32, 64);
    s0 += __shfl_down(s0, 16, 64); q0 += __shfl_down(q0, 16, 64);
    s1 += __shfl_down(s1, 16, 64); q1 += __shfl_down(q1, 16, 64);
    if (lane < 16) {
        float* bnS = bnSums + ((tile & 7) << 8);
        unsafeAtomicAdd(bnS + t0 * 16 + l16, s0);
        unsafeAtomicAdd(bnS + 128 + t0 * 16 + l16, q0);
        unsafeAtomicAdd(bnS + (t0 + 1) * 16 + l16, s1);
        unsafeAtomicAdd(bnS + 128 + (t0 + 1) * 16 + l16, q1);
    }
}

// ---------------------------------------------------------------- layer-0 BN/PReLU/L2norm -> hbf (fin computed per block)

__global__ __launch_bounds__(256) void bn_apply_kernel(const unsigned short* __restrict__ Cb,
                                unsigned short* __restrict__ hbf,
                                const float* __restrict__ bnSums,
                                const float* __restrict__ gamma, const float* __restrict__ beta,
                                const float* __restrict__ prelu_a, int layer) {
    __shared__ float finS[256];
    const int tid = threadIdx.x;
    if (tid < 128) {
        float s = 0.f, q = 0.f;
        #pragma unroll
        for (int j = 0; j < 8; ++j) { s += bnSums[j * 256 + tid]; q += bnSums[j * 256 + 128 + tid]; }
        const float invn = 1.0f / (float)NN;
        float mu = s * invn;
        float var = q * invn - mu * mu; if (var < 0.f) var = 0.f;
        finS[tid] = mu;
        finS[128 + tid] = rsqrtf(var + 1e-5f);
    }
    __syncthreads();
    const int row = blockIdx.x * 16 + (tid >> 4);
    const int li = tid & 15;
    const int p8 = li << 3;
    const float a = prelu_a[layer];
    uint4 u = *(const uint4*)(Cb + (size_t)row * 128 + p8);
    float v[8];
    v[0] = __uint_as_float(u.x << 16); v[1] = __uint_as_float(u.x & 0xffff0000u);
    v[2] = __uint_as_float(u.y << 16); v[3] = __uint_as_float(u.y & 0xffff0000u);
    v[4] = __uint_as_float(u.z << 16); v[5] = __uint_as_float(u.z & 0xffff0000u);
    v[6] = __uint_as_float(u.w << 16); v[7] = __uint_as_float(u.w & 0xffff0000u);
    float t[8]; float ss = 0.f;
    #pragma unroll
    for (int j = 0; j < 8; ++j) {
        int cc = j * 16 + li;
        float tv = (v[j] - finS[cc]) * finS[128 + cc] * gamma[cc] + beta[cc];
        tv = (tv >= 0.f) ? tv : a * tv;
        t[j] = tv; ss += tv * tv;
    }
    ss += __shfl_xor(ss, 1, 64);
    ss += __shfl_xor(ss, 2, 64);
    ss += __shfl_xor(ss, 4, 64);
    ss += __shfl_xor(ss, 8, 64);
    const float scale = 1.0f / fmaxf(sqrtf(ss), 1e-12f);
    unsigned short o[8];
    #pragma unroll
    for (int j = 0; j < 8; ++j) o[j] = f2bf(t[j] * scale);
    *(uint4*)(hbf + (size_t)row * 128 + p8) = *(uint4*)o;
}

// ---------------------------------------------------------------- layer-1 BN/PReLU/L2norm + fused pooling (fin per block)

__global__ __launch_bounds__(256) void bn_apply_pool(const unsigned short* __restrict__ Cb,
                                const float* __restrict__ bnSums,
                                const float* __restrict__ gamma, const float* __restrict__ beta,
                                const float* __restrict__ prelu_a,
                                const int* __restrict__ batch,
                                float* __restrict__ g0) {
    __shared__ float P[16][128];
    __shared__ int gids[16];
    __shared__ float finS[256];
    const int tid = threadIdx.x;
    if (tid < 128) {
        float s = 0.f, q = 0.f;
        #pragma unroll
        for (int j = 0; j < 8; ++j) { s += bnSums[j * 256 + tid]; q += bnSums[j * 256 + 128 + tid]; }
        const float invn = 1.0f / (float)NN;
        float mu = s * invn;
        float var = q * invn - mu * mu; if (var < 0.f) var = 0.f;
        finS[tid] = mu;
        finS[128 + tid] = rsqrtf(var + 1e-5f);
    }
    const int r16 = tid >> 4;
    const int li = tid & 15;
    const int row = blockIdx.x * 16 + r16;
    const int p8 = li << 3;
    if (li == 0) gids[r16] = batch[row];
    __syncthreads();
    const float a = prelu_a[1];
    uint4 u = *(const uint4*)(Cb + (size_t)row * 128 + p8);
    float v[8];
    v[0] = __uint_as_float(u.x << 16); v[1] = __uint_as_float(u.x & 0xffff0000u);
    v[2] = __uint_as_float(u.y << 16); v[3] = __uint_as_float(u.y & 0xffff0000u);
    v[4] = __uint_as_float(u.z << 16); v[5] = __uint_as_float(u.z & 0xffff0000u);
    v[6] = __uint_as_float(u.w << 16); v[7] = __uint_as_float(u.w & 0xffff0000u);
    float t[8]; float ss = 0.f;
    #pragma unroll
    for (int j = 0; j < 8; ++j) {
        int cc = j * 16 + li;
        float tv = (v[j] - finS[cc]) * finS[128 + cc] * gamma[cc] + beta[cc];
        tv = (tv >= 0.f) ? tv : a * tv;
        t[j] = tv; ss += tv * tv;
    }
    ss += __shfl_xor(ss, 1, 64);
    ss += __shfl_xor(ss, 2, 64);
    ss += __shfl_xor(ss, 4, 64);
    ss += __shfl_xor(ss, 8, 64);
    const float scale = 1.0f / fmaxf(sqrtf(ss), 1e-12f);
    #pragma unroll
    for (int j = 0; j < 8; ++j) P[r16][p8 + j] = t[j] * scale;
    __syncthreads();
    if (tid < 128) {
        int cur = gids[0];
        float run = 0.f;
        #pragma unroll
        for (int rr = 0; rr < 16; ++rr) {
            int g = gids[rr];
            if (g != cur) {
                unsafeAtomicAdd(&g0[(size_t)cur * 128 + tid], run);
                run = 0.f; cur = g;
            }
            run += P[rr][tid];
        }
        unsafeAtomicAdd(&g0[(size_t)cur * 128 + tid], run);
    }
}

// ---------------------------------------------------------------- fused MLP: fc1 (applies 1/cnt) + fc2 + out

__global__ __launch_bounds__(256) void mlp_kernel(const float* __restrict__ g,
                                                  const float* __restrict__ w1,
                                                  const float* __restrict__ b1,
                                                  const int* __restrict__ batch,
                                                  const float* __restrict__ w2,
                                                  const float* __restrict__ b2,
                                                  const float* __restrict__ outw,
                                                  const float* __restrict__ outb,
                                                  float* __restrict__ out) {
    __shared__ float g1L[256];
    __shared__ int se[2];
    __shared__ float wsum[2];
    const int row = blockIdx.x;   // 512
    const int j = threadIdx.x;    // 256
    if (j < 2) se[j] = lower_bound_dev(batch, NN, row + j);
    __syncthreads();
    const int c = se[1] - se[0];
    const float invc = 1.0f / (float)(c > 0 ? c : 1);
    float acc = 0.f;
    #pragma unroll 8
    for (int k = 0; k < 128; ++k) {
        int lk = (k & 7) * 16 + (k >> 3);         // logical feature for mem pos k
        acc += g[row * 128 + k] * w1[lk * 256 + j];
    }
    g1L[j] = fmaxf(acc * invc + b1[j], 0.f);
    __syncthreads();
    if (j < 128) {
        float acc2 = b2[j];
        #pragma unroll 8
        for (int k = 0; k < 256; ++k) acc2 += g1L[k] * w2[k * 128 + j];
        float cc = fmaxf(acc2, 0.f) * outw[j];
        cc += __shfl_down(cc, 32, 64);
        cc += __shfl_down(cc, 16, 64);
        cc += __shfl_down(cc, 8, 64);
        cc += __shfl_down(cc, 4, 64);
        cc += __shfl_down(cc, 2, 64);
        cc += __shfl_down(cc, 1, 64);
        if ((j & 63) == 0) wsum[j >> 6] = cc;
    }
    __syncthreads();
    if (j == 0) out[row] = wsum[0] + wsum[1] + outb[0];
}

// ---------------------------------------------------------------- launcher

extern "C" void kernel_launch(void* const* d_in, const int* in_sizes, int n_in,
                              void* d_out, int out_size, void* d_ws, size_t ws_size,
                              hipStream_t stream) {
    const float* x      = (const float*)d_in[0];
    const int*   eidx   = (const int*)d_in[1];
    const int*   etype  = (const int*)d_in[2];
    const int*   batch  = (const int*)d_in[3];
    const float* emb    = (const float*)d_in[4];
    const float* Wrel   = (const float*)d_in[5];
    const float* Wroot  = (const float*)d_in[6];
    const float* cbias  = (const float*)d_in[7];
    const float* gamma  = (const float*)d_in[8];
    const float* beta   = (const float*)d_in[9];
    const float* prelua = (const float*)d_in[10];
    const float* fc1w   = (const float*)d_in[11];
    const float* fc1b   = (const float*)d_in[12];
    const float* fc2w   = (const float*)d_in[13];
    const float* fc2b   = (const float*)d_in[14];
    const float* outw   = (const float*)d_in[15];
    const float* outb   = (const float*)d_in[16];
    float* out = (float*)d_out;

    const int* src = eidx;
    const int* dst = eidx + NE;

    // workspace carve-up (aligned 256B)
    char* p = (char*)d_ws;
    auto alloc = [&](size_t bytes) { char* r = p; p += (bytes + 255) & ~(size_t)255; return r; };
    unsigned short* hbf   = (unsigned short*)alloc((size_t)NN * 128 * 2);  // 25.6 MB
    unsigned short* Cb    = (unsigned short*)alloc((size_t)NN * 128 * 2);  // 25.6 MB
    unsigned* partials = (unsigned*)alloc((size_t)BPC * CHW * 4);          // 12.85 MB
    int*   sortedSrc = (int*)alloc((size_t)NE * 4);                        // 6.4 MB
    int*   srcT      = (int*)alloc((size_t)NE * 4);                        // 6.4 MB
    int*   offs      = (int*)alloc((size_t)(NN + 1) * 4);
    int*   bsums     = (int*)alloc(1024);
    int*   ntype     = (int*)alloc((size_t)NN * 4);
    unsigned short* Bf1 = (unsigned short*)alloc((size_t)81920 * 2);
    unsigned short* B0f = (unsigned short*)alloc((size_t)12288 * 2);
    float* bnSums  = (float*)alloc(2048 * 4);
    float* bnSums1 = (float*)alloc(2048 * 4);
    float* g0      = (float*)alloc((size_t)NG * 128 * 4);

    const int NBLK = (NN + 1023) / 1024;   // 98 (= CHW/256)

    // ---- weights + node types + zero inits (one kernel)
    build_weights<<<624 + (NN + 255) / 256, 256, 0, stream>>>(emb, Wroot, Wrel, x,
                                                              Bf1, B0f, ntype,
                                                              bnSums, bnSums1, g0);

    // ---- CSR build over dst (SINGLE pass; 100.4KB LDS counter table)
    hist_kernel<<<BPC, 1024, 0, stream>>>(dst, src, etype, ntype, srcT, partials);
    hr_scan1<<<NBLK, 256, 0, stream>>>(partials, offs, bsums, NN);
    scan23<<<NBLK, 256, 0, stream>>>(offs, bsums, NBLK, NN);
    place_kernel<<<BPC, 1024, 0, stream>>>(dst, srcT, offs, partials, sortedSrc);

    // ---- layer 0: fused histogram + GEMM, then BN/PReLU/L2norm
    gemm0_fused<<<(NN + 127) / 128, 256, 0, stream>>>(sortedSrc, offs, ntype, B0f,
                                                      cbias, Cb, bnSums, NN);
    bn_apply_kernel<<<NN / 16, 256, 0, stream>>>(Cb, hbf, bnSums, gamma, beta, prelua, 0);

    // ---- layer 1: fused gather + GEMM (pinned), then BN + fused pooling
    gather_gemm1<<<NN / 16, 256, 0, stream>>>(hbf, sortedSrc, offs, Bf1, cbias + 128, Cb, bnSums1);
    bn_apply_pool<<<NN / 16, 256, 0, stream>>>(Cb, bnSums1, gamma + 128, beta + 128,
                                               prelua, batch, g0);

    // ---- fused MLP
    mlp_kernel<<<NG, 256, 0, stream>>>(g0, fc1w, fc1b, batch, fc2w, fc2b, outw, outb, out);
}

// Round 11
// 323.169 us; speedup vs baseline: 1.0139x; 1.0139x over previous
//
#include <hip/hip_runtime.h>
#include <hip/hip_bf16.h>

#define NN 100000
#define NE 1600000
#define NG 512
#define CHW 25088      // u32 words, u8-packed counters for ALL 100000 keys (100.4KB LDS)
                       // = 98*256 exactly (pads keys 100000..100351 with zeros)
#define BPC 256        // blocks (edge slices) — one per CU
#define ES 6250        // NE / BPC

// Feature-column permutation: mem position p holds logical col (p&7)*16+(p>>3).
// sortedSrc payload: src[0:17) | type[17:21) | rel[21:23).  Bits >=21 are rel-only:
// this payload is part of gather_gemm1's interface.
//
// gather_gemm1 is pinned at the compulsory random-fetch floor (FETCH ~= 8 XCD x hbf,
// ~2.27 TB/s across 4 structural variants R9-R12) — and must remain BYTE-IDENTICAL:
// R17 added a single `&3` to rel extraction -> VGPR 48->56 -> occupancy 48->39% ->
// 99.6->116us (+16%). Latency-bound kernel sits on a register/occupancy cliff.
//
// R21 re-run (R10 bench was an infra failure, not a kernel failure):
// single-chunk CSR with BPC=256 (R20's BPC=128 kept per-CU edge work equal
// to R19's 2-chunk grid and idled half the CUs -> +8us). Now per-CU edge work
// HALVES (6250 loads+atomics per block) with all 256 CUs busy; partials 25.7MB.
// LESSONS: scattered global atomics over >4MB (per-XCD L2) cost ~30ns each
// (R13 place 106MB write-amp, R15 cntG +45us). Launch-count alone worth ~0.
// Work halving only helps if it shortens the per-CU critical path (R20 lesson).

typedef __attribute__((ext_vector_type(8))) short short8;
typedef __attribute__((ext_vector_type(4))) float float4v;

// ---------------------------------------------------------------- utilities

__device__ inline int lower_bound_dev(const int* __restrict__ a, int n, int v) {
    int lo = 0, hi = n;
    while (lo < hi) { int mid = (lo + hi) >> 1; if (a[mid] < v) lo = mid + 1; else hi = mid; }
    return lo;
}

__device__ inline unsigned short f2bf(float x) {
    unsigned u = __float_as_uint(x);
    unsigned r = (u + 0x7fffu + ((u >> 16) & 1u)) >> 16;   // RNE
    return (unsigned short)r;
}

// ---------------------------------------------------------------- fused prep: weights + node types + zero inits
// blocks [0,320): Bf1.  [320,368): B0f.  [368,624): g0 zero.  [624,1015): node_type.
// blocks 0-15 also zero bnSums/bnSums1.

__global__ void build_weights(const float* __restrict__ emb, const float* __restrict__ Wroot,
                              const float* __restrict__ Wrel, const float* __restrict__ x,
                              unsigned short* __restrict__ Bf, unsigned short* __restrict__ B0f,
                              int* __restrict__ ntype,
                              float* __restrict__ bnSums, float* __restrict__ bnSums1,
                              float* __restrict__ g0) {
    if (blockIdx.x < 8) bnSums[blockIdx.x * 256 + threadIdx.x] = 0.f;
    else if (blockIdx.x < 16) bnSums1[(blockIdx.x - 8) * 256 + threadIdx.x] = 0.f;
    if (blockIdx.x >= 624) {
        int i = (blockIdx.x - 624) * 256 + threadIdx.x;
        if (i < NN) {
            const float* row = x + (size_t)i * 13;
            int b = 0;
            #pragma unroll
            for (int t = 0; t < 13; ++t) if (row[t] > 0.5f) { b = t; }
            ntype[i] = b;
        }
        return;
    }
    int i = blockIdx.x * 256 + threadIdx.x;
    if (i < 81920) {
        // layer-1 fragments, k-side permuted: kcol = j*16 + ks*4 + quad
        int j = i & 7;
        int lane = (i >> 3) & 63;
        int t = (i >> 9) & 7;
        int ks = (i >> 12) & 3;
        int kc = i >> 14;
        int n = t * 16 + (lane & 15);
        int kcol = j * 16 + ks * 4 + (lane >> 4);
        float w;
        if (kc == 0) w = Wroot[16384 + (size_t)kcol * 128 + n];
        else {
            int r = kc - 1;
            w = Wrel[(((size_t)(4 + r) * 128) + kcol) * 128 + n];
        }
        Bf[i] = f2bf(w);
    } else if (i < 94208) {
        int i0 = i - 81920;          // [0, 12288)
        int j = i0 & 7;
        int lane = (i0 >> 3) & 63;
        int t = (i0 >> 9) & 7;
        int ks = i0 >> 12;
        int n = t * 16 + (lane & 15);
        int p = ks * 32 + (lane >> 4) * 8 + j;
        float val = 0.f;
        if (p < 32) {
            if (p < 13) {
                const float* er = emb + (size_t)p * 128;
                const float* wc = Wroot + n;
                float acc = 0.f;
                for (int k = 0; k < 128; ++k) acc += er[k] * wc[(size_t)k * 128];
                val = acc;
            }
        } else {
            int r = (p - 32) >> 4, tt = (p - 32) & 15;
            if (tt < 13) {
                const float* er = emb + (size_t)tt * 128;
                const float* wc = Wrel + ((size_t)r * 128) * 128 + n;
                float acc = 0.f;
                for (int k = 0; k < 128; ++k) acc += er[k] * wc[(size_t)k * 128];
                val = acc;
            }
        }
        B0f[i0] = f2bf(val);
    } else {
        int gz = i - 94208;          // [0, 65536)
        g0[gz] = 0.f;
    }
}

// ---------------------------------------------------------------- CSR build, key = dst (SINGLE pass, 256 slices)
// Each block packs srcT = src | type<<17 | rel<<21 for its own slice.

__global__ __launch_bounds__(1024) void hist_kernel(const int* __restrict__ dst,
                                                    const int* __restrict__ src,
                                                    const int* __restrict__ et,
                                                    const int* __restrict__ ntype,
                                                    int* __restrict__ srcT,
                                                    unsigned* __restrict__ partials) {
    __shared__ unsigned h[CHW];    // 100.4KB — gfx950 allows >64KB/workgroup
    const int b = blockIdx.x;
    for (int i = threadIdx.x; i < CHW; i += 1024) h[i] = 0;
    __syncthreads();
    const int e0 = b * ES;
    const int e1 = e0 + ES;        // NE = BPC*ES exact
    for (int e = e0 + threadIdx.x; e < e1; e += 1024) {
        int k = dst[e];
        atomicAdd(&h[k >> 2], 1u << ((k & 3) << 3));
        int s = src[e];
        srcT[e] = s | (ntype[s] << 17) | (et[e] << 21);
    }
    __syncthreads();
    unsigned* out = partials + (size_t)b * CHW;
    for (int i = threadIdx.x; i < CHW; i += 1024) out[i] = h[i];
}

// fused hist_reduce + scan1: per-word 256-block reduction (rewriting partials with
// running prefixes) feeds the block-local scan directly from registers.
// Block b covers keys [b*1024, b*1024+1024) = words [b*256, b*256+256); CHW = 98*256.
__global__ __launch_bounds__(256) void hr_scan1(unsigned* __restrict__ partials,
                                                int* __restrict__ offs,
                                                int* __restrict__ bsums, int n) {
    __shared__ int wsum[4];
    const int b = blockIdx.x;              // 0..97
    const int tid = threadIdx.x;
    const int i = b * 256 + tid;           // u32 word, < CHW always
    size_t base = (size_t)i;
    unsigned r0 = 0, r1 = 0, r2 = 0, r3 = 0;
    #pragma unroll 8
    for (int bb = 0; bb < BPC; ++bb) {
        unsigned t = partials[base + (size_t)bb * CHW];
        partials[base + (size_t)bb * CHW] = r0 | (r1 << 8) | (r2 << 16) | (r3 << 24);
        r0 += t & 0xffu; r1 += (t >> 8) & 0xffu; r2 += (t >> 16) & 0xffu; r3 += t >> 24;
    }
    int v[4] = {(int)r0, (int)r1, (int)r2, (int)r3};
    int loc = v[0] + v[1] + v[2] + v[3];
    const int lane = tid & 63, wid = tid >> 6;
    int sc = loc;
    #pragma unroll
    for (int o = 1; o < 64; o <<= 1) { int t = __shfl_up(sc, o, 64); if (lane >= o) sc += t; }
    if (lane == 63) wsum[wid] = sc;
    __syncthreads();
    int wbase = 0;
    for (int w = 0; w < wid; ++w) wbase += wsum[w];
    int run = wbase + sc - loc;
    const int key0 = b * 1024 + tid * 4;
    #pragma unroll
    for (int j = 0; j < 4; ++j) { int idx = key0 + j; if (idx < n) offs[idx] = run; run += v[j]; }
    if (tid == 255) bsums[b] = wbase + sc;
}

// merged scan2+scan3: each block redundantly prefix-reduces bsums (98 ints)
__global__ __launch_bounds__(256) void scan23(int* __restrict__ offs, const int* __restrict__ bsums,
                                              int nb, int n) {
    __shared__ int part[256];
    const int tid = threadIdx.x;
    int v = (tid < nb && tid < blockIdx.x) ? bsums[tid] : 0;
    part[tid] = v;
    __syncthreads();
    #pragma unroll
    for (int o = 128; o > 0; o >>= 1) {
        if (tid < o) part[tid] += part[tid + o];
        __syncthreads();
    }
    const int s = part[0];
    const int base = blockIdx.x * 1024 + tid * 4;
    #pragma unroll
    for (int j = 0; j < 4; ++j) { int idx = base + j; if (idx < n) offs[idx] += s; }
    if (blockIdx.x == (unsigned)(nb - 1) && tid == 0) offs[n] = s + bsums[nb - 1];
}

// placement: LDS u8 cursors over all keys; payload = srcT (type+rel already packed)
__global__ __launch_bounds__(1024) void place_kernel(const int* __restrict__ dst,
                                                     const int* __restrict__ srcT,
                                                     const int* __restrict__ offs,
                                                     const unsigned* __restrict__ partials,
                                                     int* __restrict__ sortedSrc) {
    __shared__ unsigned cur[CHW];  // 100.4KB
    const int b = blockIdx.x;
    const unsigned* pb = partials + (size_t)b * CHW;
    for (int i = threadIdx.x; i < CHW; i += 1024) cur[i] = pb[i];
    __syncthreads();
    const int e0 = b * ES;
    const int e1 = e0 + ES;
    for (int e = e0 + threadIdx.x; e < e1; e += 1024) {
        int key = dst[e];
        int sh = (key & 3) << 3;
        unsigned old = atomicAdd(&cur[key >> 2], 1u << sh);
        int my = (int)((old >> sh) & 0xffu);
        int pos = offs[key] + my;
        sortedSrc[pos] = srcT[e];
    }
}

// ---------------------------------------------------------------- FUSED layer-0: histogram + GEMM (K=96)
// Phase 1: all 256 threads — 2 threads per node, each walking half the edge
// range into a private cnt row (integer-exact merge). Phase 2: MFMA GEMM.
// A0L layout: [C=ks*4+quad (12)][tile(8)][l16(16)] 16B units.
// cnt and sred OVERLAY the same LDS: cnt's last read is before the post-A0-build
// barrier; sred's first write is after it (all threads pass that barrier).

__global__ __launch_bounds__(256) void gemm0_fused(const int* __restrict__ sortedSrc,
                                                   const int* __restrict__ offs,
                                                   const int* __restrict__ ntype,
                                                   const unsigned short* __restrict__ B0f,
                                                   const float* __restrict__ bias,
                                                   unsigned short* __restrict__ Cb,
                                                   float* __restrict__ bnSums, int M) {
    __shared__ unsigned short A0L[12 * 128 * 8];   // 24.6 KB
    __shared__ unsigned cntRaw[256 * 13];          // 13.3 KB, reused as sred[2][4][128]
    const int tid = threadIdx.x;
    float* sredF = (float*)cntRaw;                 // [(l*4+w)*128 + c]

    {
        const int node = tid & 127;
        const int half = tid >> 7;
        const int n = blockIdx.x * 128 + node;
        #pragma unroll
        for (int t = 0; t < 13; ++t) cntRaw[tid * 13 + t] = 0;
        if (n < M) {
            const int o0 = offs[n], o1 = offs[n + 1];
            const int mid = (o0 + o1) >> 1;
            const int lo = half ? mid : o0;
            const int hi = half ? o1 : mid;
            for (int i = lo; i < hi; ++i) {
                int v = sortedSrc[i];
                int ty = (v >> 17) & 15, r = v >> 21;
                cntRaw[tid * 13 + ty] += 1u << (r << 3);
            }
        }
    }
    __syncthreads();

    if (tid < 128) {
        const int n = blockIdx.x * 128 + tid;
        const int tile = tid >> 4, l16 = tid & 15;
        if (n < M) {
            unsigned cw[13]; unsigned relc = 0;
            #pragma unroll
            for (int t = 0; t < 13; ++t) { cw[t] = cntRaw[tid * 13 + t] + cntRaw[(tid + 128) * 13 + t]; relc += cw[t]; }
            float inv[4];
            #pragma unroll
            for (int r = 0; r < 4; ++r) {
                unsigned c = (relc >> (r << 3)) & 0xffu;
                inv[r] = 1.0f / (float)(c > 0 ? c : 1);
            }
            const int myty = ntype[n];
            #pragma unroll
            for (int ks = 0; ks < 3; ++ks) {
                #pragma unroll
                for (int quad = 0; quad < 4; ++quad) {
                    unsigned short vals[8];
                    #pragma unroll
                    for (int j = 0; j < 8; ++j) {
                        int p = ks * 32 + quad * 8 + j;
                        float v;
                        if (p < 32) v = (p == myty) ? 1.0f : 0.0f;
                        else {
                            int r = (p - 32) >> 4, tt = (p - 32) & 15;
                            v = (tt < 13) ? (float)((cw[tt] >> (r << 3)) & 0xffu) * inv[r] : 0.0f;
                        }
                        vals[j] = f2bf(v);
                    }
                    const int C = ks * 4 + quad;
                    *(uint4*)(A0L + (C * 128 + tile * 16 + l16) * 8) = *(uint4*)vals;
                }
            }
        } else {
            uint4 z; z.x = 0; z.y = 0; z.z = 0; z.w = 0;
            #pragma unroll
            for (int C = 0; C < 12; ++C)
                *(uint4*)(A0L + (C * 128 + tile * 16 + l16) * 8) = z;
        }
    }
    __syncthreads();   // after this barrier cnt is dead; sredF may be written

    // ---- GEMM phase
    const int wv = tid >> 6, lane = tid & 63;
    const int l16 = lane & 15, quad = lane >> 4;
    const int rowbase = blockIdx.x * 128 + wv * 32;
    const int tileL0 = wv * 2, tileL1 = wv * 2 + 1;

    float4v acc[2][8];
    #pragma unroll
    for (int t = 0; t < 8; ++t) {
        float bv = bias[t * 16 + l16];
        float4v av = {bv, bv, bv, bv};
        acc[0][t] = av; acc[1][t] = av;
    }

    const unsigned short* bl = B0f + lane * 8;
    #pragma unroll
    for (int ks = 0; ks < 3; ++ks) {
        const int C = ks * 4 + quad;
        short8 af0 = *(const short8*)(A0L + (C * 128 + tileL0 * 16 + l16) * 8);
        short8 af1 = *(const short8*)(A0L + (C * 128 + tileL1 * 16 + l16) * 8);
        const unsigned short* bp = bl + ((ks * 8) << 9);
        #pragma unroll
        for (int t = 0; t < 8; ++t) {
            short8 bf = *(const short8*)(bp + (t << 9));
            acc[0][t] = __builtin_amdgcn_mfma_f32_16x16x32_bf16(af0, bf, acc[0][t], 0, 0, 0);
            acc[1][t] = __builtin_amdgcn_mfma_f32_16x16x32_bf16(af1, bf, acc[1][t], 0, 0, 0);
        }
    }

    #pragma unroll
    for (int h = 0; h < 2; ++h) {
        #pragma unroll
        for (int rg = 0; rg < 4; ++rg) {
            int rr = rowbase + h * 16 + quad * 4 + rg;
            if (rr < M) {
                unsigned short v[8];
                #pragma unroll
                for (int t = 0; t < 8; ++t) v[t] = f2bf(acc[h][t][rg]);
                *(uint4*)(Cb + (size_t)rr * 128 + l16 * 8) = *(uint4*)v;
            }
        }
    }
    float s[8], q[8];
    #pragma unroll
    for (int t = 0; t < 8; ++t) {
        s[t] = 0.f; q[t] = 0.f;
        #pragma unroll
        for (int h = 0; h < 2; ++h) {
            #pragma unroll
            for (int rg = 0; rg < 4; ++rg) {
                int rr = rowbase + h * 16 + quad * 4 + rg;
                if (rr < M) { float v = acc[h][t][rg]; s[t] += v; q[t] += v * v; }
            }
        }
    }
    #pragma unroll
    for (int t = 0; t < 8; ++t) {
        s[t] += __shfl_down(s[t], 32, 64); q[t] += __shfl_down(q[t], 32, 64);
        s[t] += __shfl_down(s[t], 16, 64); q[t] += __shfl_down(q[t], 16, 64);
    }
    if (lane < 16) {
        #pragma unroll
        for (int t = 0; t < 8; ++t) {
            sredF[wv * 128 + t * 16 + l16] = s[t];        // [0][wv]
            sredF[(4 + wv) * 128 + t * 16 + l16] = q[t];  // [1][wv]
        }
    }
    __syncthreads();
    if (tid < 128) {
        float S = sredF[0 * 128 + tid] + sredF[1 * 128 + tid] + sredF[2 * 128 + tid] + sredF[3 * 128 + tid];
        float Q = sredF[4 * 128 + tid] + sredF[5 * 128 + tid] + sredF[6 * 128 + tid] + sredF[7 * 128 + tid];
        float* bnS = bnSums + ((blockIdx.x & 7) << 8);
        unsafeAtomicAdd(bnS + tid, S);
        unsafeAtomicAdd(bnS + 128 + tid, Q);
    }
}

// ---------------------------------------------------------------- FUSED layer-1: gather + GEMM (BYTE-IDENTICAL — do not touch)

__global__ __launch_bounds__(256) void gather_gemm1(const unsigned short* __restrict__ hbf,
                                                    const int* __restrict__ sortedSrc,
                                                    const int* __restrict__ offs,
                                                    const unsigned short* __restrict__ Bf,
                                                    const float* __restrict__ bias,
                                                    unsigned short* __restrict__ Cb,
                                                    float* __restrict__ bnSums) {
    __shared__ unsigned short rootL[2048];   // 4KB  (16B-unit swizzled)
    __shared__ unsigned short aggL[8192];    // 16KB (4 rel blocks, swizzled)
    const int tid = threadIdx.x;
    const int tile = blockIdx.x;
    {
        const int l16g = tid >> 4;
        const int cidx = tid & 15;
        const int c8 = cidx << 3;
        const int n = tile * 16 + l16g;                  // NN = 6250*16 exact
        const int pu = cidx * 16 + (l16g ^ cidx);        // swizzled unit
        uint4 ru = *(const uint4*)(hbf + (size_t)n * 128 + c8);
        *(uint4*)(rootL + pu * 8) = ru;

        const unsigned short* hb = hbf + c8;
        const int o0 = offs[n], o1 = offs[n + 1];

        float a0[8], a1[8], a2[8], a3[8];
        #pragma unroll
        for (int j = 0; j < 8; ++j) { a0[j] = 0.f; a1[j] = 0.f; a2[j] = 0.f; a3[j] = 0.f; }
        float c0 = 0.f, c1 = 0.f, c2 = 0.f, c3 = 0.f;

        auto body = [&](int v, uint4 u) {
            int r = v >> 21;
            float f[8];
            f[0] = __uint_as_float(u.x << 16); f[1] = __uint_as_float(u.x & 0xffff0000u);
            f[2] = __uint_as_float(u.y << 16); f[3] = __uint_as_float(u.y & 0xffff0000u);
            f[4] = __uint_as_float(u.z << 16); f[5] = __uint_as_float(u.z & 0xffff0000u);
            f[6] = __uint_as_float(u.w << 16); f[7] = __uint_as_float(u.w & 0xffff0000u);
            float m0 = (r == 0) ? 1.f : 0.f, m1 = (r == 1) ? 1.f : 0.f;
            float m2 = (r == 2) ? 1.f : 0.f, m3 = (r == 3) ? 1.f : 0.f;
            c0 += m0; c1 += m1; c2 += m2; c3 += m3;
            #pragma unroll
            for (int j = 0; j < 8; ++j) {
                a0[j] = fmaf(m0, f[j], a0[j]);
                a1[j] = fmaf(m1, f[j], a1[j]);
                a2[j] = fmaf(m2, f[j], a2[j]);
                a3[j] = fmaf(m3, f[j], a3[j]);
            }
        };

        int i = o0;
        for (; i + 4 <= o1; i += 4) {
            int v0 = sortedSrc[i], v1 = sortedSrc[i + 1];
            int v2 = sortedSrc[i + 2], v3 = sortedSrc[i + 3];
            uint4 u0 = *(const uint4*)(hb + (size_t)(v0 & 0x1ffff) * 128);
            uint4 u1 = *(const uint4*)(hb + (size_t)(v1 & 0x1ffff) * 128);
            uint4 u2 = *(const uint4*)(hb + (size_t)(v2 & 0x1ffff) * 128);
            uint4 u3 = *(const uint4*)(hb + (size_t)(v3 & 0x1ffff) * 128);
            body(v0, u0); body(v1, u1); body(v2, u2); body(v3, u3);
        }
        if (i + 2 <= o1) {
            int v0 = sortedSrc[i], v1 = sortedSrc[i + 1];
            uint4 u0 = *(const uint4*)(hb + (size_t)(v0 & 0x1ffff) * 128);
            uint4 u1 = *(const uint4*)(hb + (size_t)(v1 & 0x1ffff) * 128);
            body(v0, u0); body(v1, u1);
            i += 2;
        }
        if (i < o1) {
            int v0 = sortedSrc[i];
            uint4 u0 = *(const uint4*)(hb + (size_t)(v0 & 0x1ffff) * 128);
            body(v0, u0);
        }

        const float i0 = 1.f / fmaxf(c0, 1.f), i1 = 1.f / fmaxf(c1, 1.f);
        const float i2 = 1.f / fmaxf(c2, 1.f), i3 = 1.f / fmaxf(c3, 1.f);
        unsigned short* bp = aggL + pu * 8;
        auto pack = [&](float* a, float inv, unsigned short* dp) {
            unsigned short v[8];
            #pragma unroll
            for (int j = 0; j < 8; ++j) v[j] = f2bf(a[j] * inv);
            *(uint4*)dp = *(uint4*)v;
        };
        pack(a0, i0, bp);
        pack(a1, i1, bp + 2048);
        pack(a2, i2, bp + 4096);
        pack(a3, i3, bp + 6144);
    }
    __syncthreads();

    // ---- GEMM phase: wave wv handles output cols t0=2wv, t0+1
    const int wv = tid >> 6, lane = tid & 63;
    const int l16 = lane & 15, quad = lane >> 4;
    const int t0 = wv << 1;
    float4v acc0, acc1;
    {
        float b0v = bias[t0 * 16 + l16];
        float b1v = bias[(t0 + 1) * 16 + l16];
        float4v a0v = {b0v, b0v, b0v, b0v};
        float4v a1v = {b1v, b1v, b1v, b1v};
        acc0 = a0v; acc1 = a1v;
    }
    const unsigned short* bl = Bf + lane * 8;
    #pragma unroll
    for (int kc = 0; kc < 5; ++kc) {
        const unsigned short* Abase = (kc == 0) ? rootL : (aggL + (kc - 1) * 2048);
        #pragma unroll
        for (int ks = 0; ks < 4; ++ks) {
            const int C = ks * 4 + quad;
            const int p = C * 16 + (l16 ^ C);
            short8 af = *(const short8*)(Abase + p * 8);
            const unsigned short* bp = bl + (((kc * 4 + ks) * 8 + t0) << 9);
            short8 b0 = *(const short8*)(bp);
            short8 b1 = *(const short8*)(bp + 512);
            acc0 = __builtin_amdgcn_mfma_f32_16x16x32_bf16(af, b0, acc0, 0, 0, 0);
            acc1 = __builtin_amdgcn_mfma_f32_16x16x32_bf16(af, b1, acc1, 0, 0, 0);
        }
    }
    const int rowbase = tile * 16;
    #pragma unroll
    for (int rg = 0; rg < 4; ++rg) {
        int rr = rowbase + quad * 4 + rg;
        unsigned pk = (unsigned)f2bf(acc0[rg]) | ((unsigned)f2bf(acc1[rg]) << 16);
        *(unsigned*)(Cb + (size_t)rr * 128 + l16 * 8 + t0) = pk;
    }
    float s0 = 0.f, q0 = 0.f, s1 = 0.f, q1 = 0.f;
    #pragma unroll
    for (int rg = 0; rg < 4; ++rg) {
        float v0 = acc0[rg], v1 = acc1[rg];
        s0 += v0; q0 += v0 * v0; s1 += v1; q1 += v1 * v1;
    }
    s0 += __shfl_down(s0, 32, 64); q0 += __shfl_down(q0, 32, 64);
    s1 += __shfl_down(s1, 32, 64); q1 += __shfl_down(q1, 32, 64);
    s0 += __shfl_down(s0, 16, 64); q0 += __shfl_down(q0, 16, 64);
    s1 += __shfl_down(s1, 16, 64); q1 += __shfl_down(q1, 16, 64);
    if (lane < 16) {
        float* bnS = bnSums + ((tile & 7) << 8);
        unsafeAtomicAdd(bnS + t0 * 16 + l16, s0);
        unsafeAtomicAdd(bnS + 128 + t0 * 16 + l16, q0);
        unsafeAtomicAdd(bnS + (t0 + 1) * 16 + l16, s1);
        unsafeAtomicAdd(bnS + 128 + (t0 + 1) * 16 + l16, q1);
    }
}

// ---------------------------------------------------------------- layer-0 BN/PReLU/L2norm -> hbf (fin computed per block)

__global__ __launch_bounds__(256) void bn_apply_kernel(const unsigned short* __restrict__ Cb,
                                unsigned short* __restrict__ hbf,
                                const float* __restrict__ bnSums,
                                const float* __restrict__ gamma, const float* __restrict__ beta,
                                const float* __restrict__ prelu_a, int layer) {
    __shared__ float finS[256];
    const int tid = threadIdx.x;
    if (tid < 128) {
        float s = 0.f, q = 0.f;
        #pragma unroll
        for (int j = 0; j < 8; ++j) { s += bnSums[j * 256 + tid]; q += bnSums[j * 256 + 128 + tid]; }
        const float invn = 1.0f / (float)NN;
        float mu = s * invn;
        float var = q * invn - mu * mu; if (var < 0.f) var = 0.f;
        finS[tid] = mu;
        finS[128 + tid] = rsqrtf(var + 1e-5f);
    }
    __syncthreads();
    const int row = blockIdx.x * 16 + (tid >> 4);
    const int li = tid & 15;
    const int p8 = li << 3;
    const float a = prelu_a[layer];
    uint4 u = *(const uint4*)(Cb + (size_t)row * 128 + p8);
    float v[8];
    v[0] = __uint_as_float(u.x << 16); v[1] = __uint_as_float(u.x & 0xffff0000u);
    v[2] = __uint_as_float(u.y << 16); v[3] = __uint_as_float(u.y & 0xffff0000u);
    v[4] = __uint_as_float(u.z << 16); v[5] = __uint_as_float(u.z & 0xffff0000u);
    v[6] = __uint_as_float(u.w << 16); v[7] = __uint_as_float(u.w & 0xffff0000u);
    float t[8]; float ss = 0.f;
    #pragma unroll
    for (int j = 0; j < 8; ++j) {
        int cc = j * 16 + li;
        float tv = (v[j] - finS[cc]) * finS[128 + cc] * gamma[cc] + beta[cc];
        tv = (tv >= 0.f) ? tv : a * tv;
        t[j] = tv; ss += tv * tv;
    }
    ss += __shfl_xor(ss, 1, 64);
    ss += __shfl_xor(ss, 2, 64);
    ss += __shfl_xor(ss, 4, 64);
    ss += __shfl_xor(ss, 8, 64);
    const float scale = 1.0f / fmaxf(sqrtf(ss), 1e-12f);
    unsigned short o[8];
    #pragma unroll
    for (int j = 0; j < 8; ++j) o[j] = f2bf(t[j] * scale);
    *(uint4*)(hbf + (size_t)row * 128 + p8) = *(uint4*)o;
}

// ---------------------------------------------------------------- layer-1 BN/PReLU/L2norm + fused pooling (fin per block)

__global__ __launch_bounds__(256) void bn_apply_pool(const unsigned short* __restrict__ Cb,
                                const float* __restrict__ bnSums,
                                const float* __restrict__ gamma, const float* __restrict__ beta,
                                const float* __restrict__ prelu_a,
                                const int* __restrict__ batch,
                                float* __restrict__ g0) {
    __shared__ float P[16][128];
    __shared__ int gids[16];
    __shared__ float finS[256];
    const int tid = threadIdx.x;
    if (tid < 128) {
        float s = 0.f, q = 0.f;
        #pragma unroll
        for (int j = 0; j < 8; ++j) { s += bnSums[j * 256 + tid]; q += bnSums[j * 256 + 128 + tid]; }
        const float invn = 1.0f / (float)NN;
        float mu = s * invn;
        float var = q * invn - mu * mu; if (var < 0.f) var = 0.f;
        finS[tid] = mu;
        finS[128 + tid] = rsqrtf(var + 1e-5f);
    }
    const int r16 = tid >> 4;
    const int li = tid & 15;
    const int row = blockIdx.x * 16 + r16;
    const int p8 = li << 3;
    if (li == 0) gids[r16] = batch[row];
    __syncthreads();
    const float a = prelu_a[1];
    uint4 u = *(const uint4*)(Cb + (size_t)row * 128 + p8);
    float v[8];
    v[0] = __uint_as_float(u.x << 16); v[1] = __uint_as_float(u.x & 0xffff0000u);
    v[2] = __uint_as_float(u.y << 16); v[3] = __uint_as_float(u.y & 0xffff0000u);
    v[4] = __uint_as_float(u.z << 16); v[5] = __uint_as_float(u.z & 0xffff0000u);
    v[6] = __uint_as_float(u.w << 16); v[7] = __uint_as_float(u.w & 0xffff0000u);
    float t[8]; float ss = 0.f;
    #pragma unroll
    for (int j = 0; j < 8; ++j) {
        int cc = j * 16 + li;
        float tv = (v[j] - finS[cc]) * finS[128 + cc] * gamma[cc] + beta[cc];
        tv = (tv >= 0.f) ? tv : a * tv;
        t[j] = tv; ss += tv * tv;
    }
    ss += __shfl_xor(ss, 1, 64);
    ss += __shfl_xor(ss, 2, 64);
    ss += __shfl_xor(ss, 4, 64);
    ss += __shfl_xor(ss, 8, 64);
    const float scale = 1.0f / fmaxf(sqrtf(ss), 1e-12f);
    #pragma unroll
    for (int j = 0; j < 8; ++j) P[r16][p8 + j] = t[j] * scale;
    __syncthreads();
    if (tid < 128) {
        int cur = gids[0];
        float run = 0.f;
        #pragma unroll
        for (int rr = 0; rr < 16; ++rr) {
            int g = gids[rr];
            if (g != cur) {
                unsafeAtomicAdd(&g0[(size_t)cur * 128 + tid], run);
                run = 0.f; cur = g;
            }
            run += P[rr][tid];
        }
        unsafeAtomicAdd(&g0[(size_t)cur * 128 + tid], run);
    }
}

// ---------------------------------------------------------------- fused MLP: fc1 (applies 1/cnt) + fc2 + out

__global__ __launch_bounds__(256) void mlp_kernel(const float* __restrict__ g,
                                                  const float* __restrict__ w1,
                                                  const float* __restrict__ b1,
                                                  const int* __restrict__ batch,
                                                  const float* __restrict__ w2,
                                                  const float* __restrict__ b2,
                                                  const float* __restrict__ outw,
                                                  const float* __restrict__ outb,
                                                  float* __restrict__ out) {
    __shared__ float g1L[256];
    __shared__ int se[2];
    __shared__ float wsum[2];
    const int row = blockIdx.x;   // 512
    const int j = threadIdx.x;    // 256
    if (j < 2) se[j] = lower_bound_dev(batch, NN, row + j);
    __syncthreads();
    const int c = se[1] - se[0];
    const float invc = 1.0f / (float)(c > 0 ? c : 1);
    float acc = 0.f;
    #pragma unroll 8
    for (int k = 0; k < 128; ++k) {
        int lk = (k & 7) * 16 + (k >> 3);         // logical feature for mem pos k
        acc += g[row * 128 + k] * w1[lk * 256 + j];
    }
    g1L[j] = fmaxf(acc * invc + b1[j], 0.f);
    __syncthreads();
    if (j < 128) {
        float acc2 = b2[j];
        #pragma unroll 8
        for (int k = 0; k < 256; ++k) acc2 += g1L[k] * w2[k * 128 + j];
        float cc = fmaxf(acc2, 0.f) * outw[j];
        cc += __shfl_down(cc, 32, 64);
        cc += __shfl_down(cc, 16, 64);
        cc += __shfl_down(cc, 8, 64);
        cc += __shfl_down(cc, 4, 64);
        cc += __shfl_down(cc, 2, 64);
        cc += __shfl_down(cc, 1, 64);
        if ((j & 63) == 0) wsum[j >> 6] = cc;
    }
    __syncthreads();
    if (j == 0) out[row] = wsum[0] + wsum[1] + outb[0];
}

// ---------------------------------------------------------------- launcher

extern "C" void kernel_launch(void* const* d_in, const int* in_sizes, int n_in,
                              void* d_out, int out_size, void* d_ws, size_t ws_size,
                              hipStream_t stream) {
    const float* x      = (const float*)d_in[0];
    const int*   eidx   = (const int*)d_in[1];
    const int*   etype  = (const int*)d_in[2];
    const int*   batch  = (const int*)d_in[3];
    const float* emb    = (const float*)d_in[4];
    const float* Wrel   = (const float*)d_in[5];
    const float* Wroot  = (const float*)d_in[6];
    const float* cbias  = (const float*)d_in[7];
    const float* gamma  = (const float*)d_in[8];
    const float* beta   = (const float*)d_in[9];
    const float* prelua = (const float*)d_in[10];
    const float* fc1w   = (const float*)d_in[11];
    const float* fc1b   = (const float*)d_in[12];
    const float* fc2w   = (const float*)d_in[13];
    const float* fc2b   = (const float*)d_in[14];
    const float* outw   = (const float*)d_in[15];
    const float* outb   = (const float*)d_in[16];
    float* out = (float*)d_out;

    const int* src = eidx;
    const int* dst = eidx + NE;

    // workspace carve-up (aligned 256B)
    char* p = (char*)d_ws;
    auto alloc = [&](size_t bytes) { char* r = p; p += (bytes + 255) & ~(size_t)255; return r; };
    unsigned short* hbf   = (unsigned short*)alloc((size_t)NN * 128 * 2);  // 25.6 MB
    unsigned short* Cb    = (unsigned short*)alloc((size_t)NN * 128 * 2);  // 25.6 MB
    unsigned* partials = (unsigned*)alloc((size_t)BPC * CHW * 4);          // 25.7 MB
    int*   sortedSrc = (int*)alloc((size_t)NE * 4);                        // 6.4 MB
    int*   srcT      = (int*)alloc((size_t)NE * 4);                        // 6.4 MB
    int*   offs      = (int*)alloc((size_t)(NN + 1) * 4);
    int*   bsums     = (int*)alloc(1024);
    int*   ntype     = (int*)alloc((size_t)NN * 4);
    unsigned short* Bf1 = (unsigned short*)alloc((size_t)81920 * 2);
    unsigned short* B0f = (unsigned short*)alloc((size_t)12288 * 2);
    float* bnSums  = (float*)alloc(2048 * 4);
    float* bnSums1 = (float*)alloc(2048 * 4);
    float* g0      = (float*)alloc((size_t)NG * 128 * 4);

    const int NBLK = (NN + 1023) / 1024;   // 98 (= CHW/256)

    // ---- weights + node types + zero inits (one kernel)
    build_weights<<<624 + (NN + 255) / 256, 256, 0, stream>>>(emb, Wroot, Wrel, x,
                                                              Bf1, B0f, ntype,
                                                              bnSums, bnSums1, g0);

    // ---- CSR build over dst (single pass, 256 slices; 100.4KB LDS counter table)
    hist_kernel<<<BPC, 1024, 0, stream>>>(dst, src, etype, ntype, srcT, partials);
    hr_scan1<<<NBLK, 256, 0, stream>>>(partials, offs, bsums, NN);
    scan23<<<NBLK, 256, 0, stream>>>(offs, bsums, NBLK, NN);
    place_kernel<<<BPC, 1024, 0, stream>>>(dst, srcT, offs, partials, sortedSrc);

    // ---- layer 0: fused histogram + GEMM, then BN/PReLU/L2norm
    gemm0_fused<<<(NN + 127) / 128, 256, 0, stream>>>(sortedSrc, offs, ntype, B0f,
                                                      cbias, Cb, bnSums, NN);
    bn_apply_kernel<<<NN / 16, 256, 0, stream>>>(Cb, hbf, bnSums, gamma, beta, prelua, 0);

    // ---- layer 1: fused gather + GEMM (pinned), then BN + fused pooling
    gather_gemm1<<<NN / 16, 256, 0, stream>>>(hbf, sortedSrc, offs, Bf1, cbias + 128, Cb, bnSums1);
    bn_apply_pool<<<NN / 16, 256, 0, stream>>>(Cb, bnSums1, gamma + 128, beta + 128,
                                               prelua, batch, g0);

    // ---- fused MLP
    mlp_kernel<<<NG, 256, 0, stream>>>(g0, fc1w, fc1b, batch, fc2w, fc2b, outw, outb, out);
}

// Round 12
// 316.398 us; speedup vs baseline: 1.0356x; 1.0214x over previous
//
#include <hip/hip_runtime.h>
#include <hip/hip_bf16.h>

#define NN 100000
#define NE 1600000
#define NG 512
#define CH3 65536      // keys per chunk (u8-packed counters: 16384 u32 = 64KB LDS)
#define CHW 16384      // u32 words per chunk
#define NCH 2          // ceil(100000/65536)
#define BPC 128        // blocks per chunk
#define ES 12500       // NE / BPC

// Feature-column permutation: mem position p holds logical col (p&7)*16+(p>>3).
// sortedSrc payload: src[0:17) | type[17:21) | rel[21:23).  Bits >=21 are rel-only:
// this payload is part of gather_gemm1's interface.
//
// gather_gemm1 is pinned at the compulsory random-fetch floor (FETCH ~= 8 XCD x hbf,
// ~2.27 TB/s across 4 structural variants R9-R12) — and must remain BYTE-IDENTICAL:
// R17 added a single `&3` to rel extraction -> VGPR 48->56 -> occupancy 48->39% ->
// 99.6->116us (+16%). Latency-bound kernel sits on a register/occupancy cliff.
//
// R22 = exact revert to R19 (proven 319.66us best).
// CSR-build design space is CLOSED at this configuration:
//  - R13/R15: scattered global atomics over >4MB (per-XCD L2) cost ~30ns each
//    (place write-amp 106MB; cntG +45us).
//  - R20: single-chunk BPC=128 kept per-CU edge work equal while idling half
//    the CUs (+8us) — work halving must shorten the per-CU critical path.
//  - R21: single-chunk BPC=256 halves edge chains but pays +53% LDS table
//    zero/flush, +9MB partials x3 passes, and 2x hr_scan1 depth (+3.5us net).
// Launch-count alone worth ~0. 2-chunk/64KB-LDS/1024-thread is the local optimum.

typedef __attribute__((ext_vector_type(8))) short short8;
typedef __attribute__((ext_vector_type(4))) float float4v;

// ---------------------------------------------------------------- utilities

__device__ inline int lower_bound_dev(const int* __restrict__ a, int n, int v) {
    int lo = 0, hi = n;
    while (lo < hi) { int mid = (lo + hi) >> 1; if (a[mid] < v) lo = mid + 1; else hi = mid; }
    return lo;
}

__device__ inline unsigned short f2bf(float x) {
    unsigned u = __float_as_uint(x);
    unsigned r = (u + 0x7fffu + ((u >> 16) & 1u)) >> 16;   // RNE
    return (unsigned short)r;
}

// ---------------------------------------------------------------- fused prep: weights + node types + zero inits
// blocks [0,320): Bf1.  [320,368): B0f.  [368,624): g0 zero.  [624,1015): node_type.
// blocks 0-15 also zero bnSums/bnSums1.

__global__ void build_weights(const float* __restrict__ emb, const float* __restrict__ Wroot,
                              const float* __restrict__ Wrel, const float* __restrict__ x,
                              unsigned short* __restrict__ Bf, unsigned short* __restrict__ B0f,
                              int* __restrict__ ntype,
                              float* __restrict__ bnSums, float* __restrict__ bnSums1,
                              float* __restrict__ g0) {
    if (blockIdx.x < 8) bnSums[blockIdx.x * 256 + threadIdx.x] = 0.f;
    else if (blockIdx.x < 16) bnSums1[(blockIdx.x - 8) * 256 + threadIdx.x] = 0.f;
    if (blockIdx.x >= 624) {
        int i = (blockIdx.x - 624) * 256 + threadIdx.x;
        if (i < NN) {
            const float* row = x + (size_t)i * 13;
            int b = 0;
            #pragma unroll
            for (int t = 0; t < 13; ++t) if (row[t] > 0.5f) { b = t; }
            ntype[i] = b;
        }
        return;
    }
    int i = blockIdx.x * 256 + threadIdx.x;
    if (i < 81920) {
        // layer-1 fragments, k-side permuted: kcol = j*16 + ks*4 + quad
        int j = i & 7;
        int lane = (i >> 3) & 63;
        int t = (i >> 9) & 7;
        int ks = (i >> 12) & 3;
        int kc = i >> 14;
        int n = t * 16 + (lane & 15);
        int kcol = j * 16 + ks * 4 + (lane >> 4);
        float w;
        if (kc == 0) w = Wroot[16384 + (size_t)kcol * 128 + n];
        else {
            int r = kc - 1;
            w = Wrel[(((size_t)(4 + r) * 128) + kcol) * 128 + n];
        }
        Bf[i] = f2bf(w);
    } else if (i < 94208) {
        int i0 = i - 81920;          // [0, 12288)
        int j = i0 & 7;
        int lane = (i0 >> 3) & 63;
        int t = (i0 >> 9) & 7;
        int ks = i0 >> 12;
        int n = t * 16 + (lane & 15);
        int p = ks * 32 + (lane >> 4) * 8 + j;
        float val = 0.f;
        if (p < 32) {
            if (p < 13) {
                const float* er = emb + (size_t)p * 128;
                const float* wc = Wroot + n;
                float acc = 0.f;
                for (int k = 0; k < 128; ++k) acc += er[k] * wc[(size_t)k * 128];
                val = acc;
            }
        } else {
            int r = (p - 32) >> 4, tt = (p - 32) & 15;
            if (tt < 13) {
                const float* er = emb + (size_t)tt * 128;
                const float* wc = Wrel + ((size_t)r * 128) * 128 + n;
                float acc = 0.f;
                for (int k = 0; k < 128; ++k) acc += er[k] * wc[(size_t)k * 128];
                val = acc;
            }
        }
        B0f[i0] = f2bf(val);
    } else {
        int gz = i - 94208;          // [0, 65536)
        g0[gz] = 0.f;
    }
}

// ---------------------------------------------------------------- CSR build, key = dst (2 chunk passes)
// chunk-0 blocks also pack srcT = src | type<<17 | rel<<21 for their edge slice.
// 1024 threads/block: 64KB-LDS kernel needs the extra waves for latency hiding.

__global__ __launch_bounds__(1024) void hist_kernel(const int* __restrict__ dst,
                                                    const int* __restrict__ src,
                                                    const int* __restrict__ et,
                                                    const int* __restrict__ ntype,
                                                    int* __restrict__ srcT,
                                                    unsigned* __restrict__ partials) {
    __shared__ unsigned h[CHW];
    const int b = blockIdx.x, c = blockIdx.y;
    const int lo = c * CH3;
    for (int i = threadIdx.x; i < CHW; i += 1024) h[i] = 0;
    __syncthreads();
    const int e0 = b * ES;
    const int e1 = (e0 + ES < NE) ? e0 + ES : NE;
    if (c == 0) {
        for (int e = e0 + threadIdx.x; e < e1; e += 1024) {
            int k = dst[e] - lo;
            if (k >= 0 && k < CH3) atomicAdd(&h[k >> 2], 1u << ((k & 3) << 3));
            int s = src[e];
            srcT[e] = s | (ntype[s] << 17) | (et[e] << 21);
        }
    } else {
        for (int e = e0 + threadIdx.x; e < e1; e += 1024) {
            int k = dst[e] - lo;
            if (k >= 0 && k < CH3) atomicAdd(&h[k >> 2], 1u << ((k & 3) << 3));
        }
    }
    __syncthreads();
    unsigned* out = partials + ((size_t)(c * BPC + b)) * CHW;
    for (int i = threadIdx.x; i < CHW; i += 1024) out[i] = h[i];
}

// fused hist_reduce + scan1: per-word 128-block reduction (rewriting partials with
// running prefixes) feeds the block-local scan directly from registers.
// Block b covers keys [b*1024, b*1024+1024); 1024-aligned blocks never straddle
// the 65536 chunk boundary.
__global__ __launch_bounds__(256) void hr_scan1(unsigned* __restrict__ partials,
                                                int* __restrict__ offs,
                                                int* __restrict__ bsums, int n) {
    __shared__ int wsum[4];
    const int b = blockIdx.x;              // 0..97
    const int tid = threadIdx.x;
    const int c = b >> 6;                  // chunk
    const int i = (b & 63) * 256 + tid;    // u32 word within chunk
    size_t base = (size_t)c * BPC * CHW + i;
    unsigned r0 = 0, r1 = 0, r2 = 0, r3 = 0;
    #pragma unroll 8
    for (int bb = 0; bb < BPC; ++bb) {
        unsigned t = partials[base + (size_t)bb * CHW];
        partials[base + (size_t)bb * CHW] = r0 | (r1 << 8) | (r2 << 16) | (r3 << 24);
        r0 += t & 0xffu; r1 += (t >> 8) & 0xffu; r2 += (t >> 16) & 0xffu; r3 += t >> 24;
    }
    int v[4] = {(int)r0, (int)r1, (int)r2, (int)r3};
    int loc = v[0] + v[1] + v[2] + v[3];
    const int lane = tid & 63, wid = tid >> 6;
    int sc = loc;
    #pragma unroll
    for (int o = 1; o < 64; o <<= 1) { int t = __shfl_up(sc, o, 64); if (lane >= o) sc += t; }
    if (lane == 63) wsum[wid] = sc;
    __syncthreads();
    int wbase = 0;
    for (int w = 0; w < wid; ++w) wbase += wsum[w];
    int run = wbase + sc - loc;
    const int key0 = b * 1024 + tid * 4;
    #pragma unroll
    for (int j = 0; j < 4; ++j) { int idx = key0 + j; if (idx < n) offs[idx] = run; run += v[j]; }
    if (tid == 255) bsums[b] = wbase + sc;
}

// merged scan2+scan3: each block redundantly prefix-reduces bsums (98 ints)
__global__ __launch_bounds__(256) void scan23(int* __restrict__ offs, const int* __restrict__ bsums,
                                              int nb, int n) {
    __shared__ int part[256];
    const int tid = threadIdx.x;
    int v = (tid < nb && tid < blockIdx.x) ? bsums[tid] : 0;
    part[tid] = v;
    __syncthreads();
    #pragma unroll
    for (int o = 128; o > 0; o >>= 1) {
        if (tid < o) part[tid] += part[tid + o];
        __syncthreads();
    }
    const int s = part[0];
    const int base = blockIdx.x * 1024 + tid * 4;
    #pragma unroll
    for (int j = 0; j < 4; ++j) { int idx = base + j; if (idx < n) offs[idx] += s; }
    if (blockIdx.x == (unsigned)(nb - 1) && tid == 0) offs[n] = s + bsums[nb - 1];
}

// placement: LDS u8 cursors; payload = srcT (type+rel already packed)
// 1024 threads/block (same rationale as hist).
__global__ __launch_bounds__(1024) void place_kernel(const int* __restrict__ dst,
                                                     const int* __restrict__ srcT,
                                                     const int* __restrict__ offs,
                                                     const unsigned* __restrict__ partials,
                                                     int* __restrict__ sortedSrc) {
    __shared__ unsigned cur[CHW];
    const int b = blockIdx.x, c = blockIdx.y;
    const int lo = c * CH3;
    const unsigned* pb = partials + ((size_t)(c * BPC + b)) * CHW;
    for (int i = threadIdx.x; i < CHW; i += 1024) cur[i] = pb[i];
    __syncthreads();
    const int e0 = b * ES;
    const int e1 = (e0 + ES < NE) ? e0 + ES : NE;
    for (int e = e0 + threadIdx.x; e < e1; e += 1024) {
        int key = dst[e];
        int k = key - lo;
        if (k >= 0 && k < CH3) {
            int sh = (k & 3) << 3;
            unsigned old = atomicAdd(&cur[k >> 2], 1u << sh);
            int my = (int)((old >> sh) & 0xffu);
            int pos = offs[key] + my;
            sortedSrc[pos] = srcT[e];
        }
    }
}

// ---------------------------------------------------------------- FUSED layer-0: histogram + GEMM (K=96)
// Phase 1: all 256 threads — 2 threads per node, each walking half the edge
// range into a private cnt row (integer-exact merge). Phase 2: MFMA GEMM.
// A0L layout: [C=ks*4+quad (12)][tile(8)][l16(16)] 16B units.
// cnt and sred OVERLAY the same LDS: cnt's last read is before the post-A0-build
// barrier; sred's first write is after it (all threads pass that barrier).

__global__ __launch_bounds__(256) void gemm0_fused(const int* __restrict__ sortedSrc,
                                                   const int* __restrict__ offs,
                                                   const int* __restrict__ ntype,
                                                   const unsigned short* __restrict__ B0f,
                                                   const float* __restrict__ bias,
                                                   unsigned short* __restrict__ Cb,
                                                   float* __restrict__ bnSums, int M) {
    __shared__ unsigned short A0L[12 * 128 * 8];   // 24.6 KB
    __shared__ unsigned cntRaw[256 * 13];          // 13.3 KB, reused as sred[2][4][128]
    const int tid = threadIdx.x;
    float* sredF = (float*)cntRaw;                 // [(l*4+w)*128 + c]

    {
        const int node = tid & 127;
        const int half = tid >> 7;
        const int n = blockIdx.x * 128 + node;
        #pragma unroll
        for (int t = 0; t < 13; ++t) cntRaw[tid * 13 + t] = 0;
        if (n < M) {
            const int o0 = offs[n], o1 = offs[n + 1];
            const int mid = (o0 + o1) >> 1;
            const int lo = half ? mid : o0;
            const int hi = half ? o1 : mid;
            for (int i = lo; i < hi; ++i) {
                int v = sortedSrc[i];
                int ty = (v >> 17) & 15, r = v >> 21;
                cntRaw[tid * 13 + ty] += 1u << (r << 3);
            }
        }
    }
    __syncthreads();

    if (tid < 128) {
        const int n = blockIdx.x * 128 + tid;
        const int tile = tid >> 4, l16 = tid & 15;
        if (n < M) {
            unsigned cw[13]; unsigned relc = 0;
            #pragma unroll
            for (int t = 0; t < 13; ++t) { cw[t] = cntRaw[tid * 13 + t] + cntRaw[(tid + 128) * 13 + t]; relc += cw[t]; }
            float inv[4];
            #pragma unroll
            for (int r = 0; r < 4; ++r) {
                unsigned c = (relc >> (r << 3)) & 0xffu;
                inv[r] = 1.0f / (float)(c > 0 ? c : 1);
            }
            const int myty = ntype[n];
            #pragma unroll
            for (int ks = 0; ks < 3; ++ks) {
                #pragma unroll
                for (int quad = 0; quad < 4; ++quad) {
                    unsigned short vals[8];
                    #pragma unroll
                    for (int j = 0; j < 8; ++j) {
                        int p = ks * 32 + quad * 8 + j;
                        float v;
                        if (p < 32) v = (p == myty) ? 1.0f : 0.0f;
                        else {
                            int r = (p - 32) >> 4, tt = (p - 32) & 15;
                            v = (tt < 13) ? (float)((cw[tt] >> (r << 3)) & 0xffu) * inv[r] : 0.0f;
                        }
                        vals[j] = f2bf(v);
                    }
                    const int C = ks * 4 + quad;
                    *(uint4*)(A0L + (C * 128 + tile * 16 + l16) * 8) = *(uint4*)vals;
                }
            }
        } else {
            uint4 z; z.x = 0; z.y = 0; z.z = 0; z.w = 0;
            #pragma unroll
            for (int C = 0; C < 12; ++C)
                *(uint4*)(A0L + (C * 128 + tile * 16 + l16) * 8) = z;
        }
    }
    __syncthreads();   // after this barrier cnt is dead; sredF may be written

    // ---- GEMM phase
    const int wv = tid >> 6, lane = tid & 63;
    const int l16 = lane & 15, quad = lane >> 4;
    const int rowbase = blockIdx.x * 128 + wv * 32;
    const int tileL0 = wv * 2, tileL1 = wv * 2 + 1;

    float4v acc[2][8];
    #pragma unroll
    for (int t = 0; t < 8; ++t) {
        float bv = bias[t * 16 + l16];
        float4v av = {bv, bv, bv, bv};
        acc[0][t] = av; acc[1][t] = av;
    }

    const unsigned short* bl = B0f + lane * 8;
    #pragma unroll
    for (int ks = 0; ks < 3; ++ks) {
        const int C = ks * 4 + quad;
        short8 af0 = *(const short8*)(A0L + (C * 128 + tileL0 * 16 + l16) * 8);
        short8 af1 = *(const short8*)(A0L + (C * 128 + tileL1 * 16 + l16) * 8);
        const unsigned short* bp = bl + ((ks * 8) << 9);
        #pragma unroll
        for (int t = 0; t < 8; ++t) {
            short8 bf = *(const short8*)(bp + (t << 9));
            acc[0][t] = __builtin_amdgcn_mfma_f32_16x16x32_bf16(af0, bf, acc[0][t], 0, 0, 0);
            acc[1][t] = __builtin_amdgcn_mfma_f32_16x16x32_bf16(af1, bf, acc[1][t], 0, 0, 0);
        }
    }

    #pragma unroll
    for (int h = 0; h < 2; ++h) {
        #pragma unroll
        for (int rg = 0; rg < 4; ++rg) {
            int rr = rowbase + h * 16 + quad * 4 + rg;
            if (rr < M) {
                unsigned short v[8];
                #pragma unroll
                for (int t = 0; t < 8; ++t) v[t] = f2bf(acc[h][t][rg]);
                *(uint4*)(Cb + (size_t)rr * 128 + l16 * 8) = *(uint4*)v;
            }
        }
    }
    float s[8], q[8];
    #pragma unroll
    for (int t = 0; t < 8; ++t) {
        s[t] = 0.f; q[t] = 0.f;
        #pragma unroll
        for (int h = 0; h < 2; ++h) {
            #pragma unroll
            for (int rg = 0; rg < 4; ++rg) {
                int rr = rowbase + h * 16 + quad * 4 + rg;
                if (rr < M) { float v = acc[h][t][rg]; s[t] += v; q[t] += v * v; }
            }
        }
    }
    #pragma unroll
    for (int t = 0; t < 8; ++t) {
        s[t] += __shfl_down(s[t], 32, 64); q[t] += __shfl_down(q[t], 32, 64);
        s[t] += __shfl_down(s[t], 16, 64); q[t] += __shfl_down(q[t], 16, 64);
    }
    if (lane < 16) {
        #pragma unroll
        for (int t = 0; t < 8; ++t) {
            sredF[wv * 128 + t * 16 + l16] = s[t];        // [0][wv]
            sredF[(4 + wv) * 128 + t * 16 + l16] = q[t];  // [1][wv]
        }
    }
    __syncthreads();
    if (tid < 128) {
        float S = sredF[0 * 128 + tid] + sredF[1 * 128 + tid] + sredF[2 * 128 + tid] + sredF[3 * 128 + tid];
        float Q = sredF[4 * 128 + tid] + sredF[5 * 128 + tid] + sredF[6 * 128 + tid] + sredF[7 * 128 + tid];
        float* bnS = bnSums + ((blockIdx.x & 7) << 8);
        unsafeAtomicAdd(bnS + tid, S);
        unsafeAtomicAdd(bnS + 128 + tid, Q);
    }
}

// ---------------------------------------------------------------- FUSED layer-1: gather + GEMM (BYTE-IDENTICAL — do not touch)

__global__ __launch_bounds__(256) void gather_gemm1(const unsigned short* __restrict__ hbf,
                                                    const int* __restrict__ sortedSrc,
                                                    const int* __restrict__ offs,
                                                    const unsigned short* __restrict__ Bf,
                                                    const float* __restrict__ bias,
                                                    unsigned short* __restrict__ Cb,
                                                    float* __restrict__ bnSums) {
    __shared__ unsigned short rootL[2048];   // 4KB  (16B-unit swizzled)
    __shared__ unsigned short aggL[8192];    // 16KB (4 rel blocks, swizzled)
    const int tid = threadIdx.x;
    const int tile = blockIdx.x;
    {
        const int l16g = tid >> 4;
        const int cidx = tid & 15;
        const int c8 = cidx << 3;
        const int n = tile * 16 + l16g;                  // NN = 6250*16 exact
        const int pu = cidx * 16 + (l16g ^ cidx);        // swizzled unit
        uint4 ru = *(const uint4*)(hbf + (size_t)n * 128 + c8);
        *(uint4*)(rootL + pu * 8) = ru;

        const unsigned short* hb = hbf + c8;
        const int o0 = offs[n], o1 = offs[n + 1];

        float a0[8], a1[8], a2[8], a3[8];
        #pragma unroll
        for (int j = 0; j < 8; ++j) { a0[j] = 0.f; a1[j] = 0.f; a2[j] = 0.f; a3[j] = 0.f; }
        float c0 = 0.f, c1 = 0.f, c2 = 0.f, c3 = 0.f;

        auto body = [&](int v, uint4 u) {
            int r = v >> 21;
            float f[8];
            f[0] = __uint_as_float(u.x << 16); f[1] = __uint_as_float(u.x & 0xffff0000u);
            f[2] = __uint_as_float(u.y << 16); f[3] = __uint_as_float(u.y & 0xffff0000u);
            f[4] = __uint_as_float(u.z << 16); f[5] = __uint_as_float(u.z & 0xffff0000u);
            f[6] = __uint_as_float(u.w << 16); f[7] = __uint_as_float(u.w & 0xffff0000u);
            float m0 = (r == 0) ? 1.f : 0.f, m1 = (r == 1) ? 1.f : 0.f;
            float m2 = (r == 2) ? 1.f : 0.f, m3 = (r == 3) ? 1.f : 0.f;
            c0 += m0; c1 += m1; c2 += m2; c3 += m3;
            #pragma unroll
            for (int j = 0; j < 8; ++j) {
                a0[j] = fmaf(m0, f[j], a0[j]);
                a1[j] = fmaf(m1, f[j], a1[j]);
                a2[j] = fmaf(m2, f[j], a2[j]);
                a3[j] = fmaf(m3, f[j], a3[j]);
            }
        };

        int i = o0;
        for (; i + 4 <= o1; i += 4) {
            int v0 = sortedSrc[i], v1 = sortedSrc[i + 1];
            int v2 = sortedSrc[i + 2], v3 = sortedSrc[i + 3];
            uint4 u0 = *(const uint4*)(hb + (size_t)(v0 & 0x1ffff) * 128);
            uint4 u1 = *(const uint4*)(hb + (size_t)(v1 & 0x1ffff) * 128);
            uint4 u2 = *(const uint4*)(hb + (size_t)(v2 & 0x1ffff) * 128);
            uint4 u3 = *(const uint4*)(hb + (size_t)(v3 & 0x1ffff) * 128);
            body(v0, u0); body(v1, u1); body(v2, u2); body(v3, u3);
        }
        if (i + 2 <= o1) {
            int v0 = sortedSrc[i], v1 = sortedSrc[i + 1];
            uint4 u0 = *(const uint4*)(hb + (size_t)(v0 & 0x1ffff) * 128);
            uint4 u1 = *(const uint4*)(hb + (size_t)(v1 & 0x1ffff) * 128);
            body(v0, u0); body(v1, u1);
            i += 2;
        }
        if (i < o1) {
            int v0 = sortedSrc[i];
            uint4 u0 = *(const uint4*)(hb + (size_t)(v0 & 0x1ffff) * 128);
            body(v0, u0);
        }

        const float i0 = 1.f / fmaxf(c0, 1.f), i1 = 1.f / fmaxf(c1, 1.f);
        const float i2 = 1.f / fmaxf(c2, 1.f), i3 = 1.f / fmaxf(c3, 1.f);
        unsigned short* bp = aggL + pu * 8;
        auto pack = [&](float* a, float inv, unsigned short* dp) {
            unsigned short v[8];
            #pragma unroll
            for (int j = 0; j < 8; ++j) v[j] = f2bf(a[j] * inv);
            *(uint4*)dp = *(uint4*)v;
        };
        pack(a0, i0, bp);
        pack(a1, i1, bp + 2048);
        pack(a2, i2, bp + 4096);
        pack(a3, i3, bp + 6144);
    }
    __syncthreads();

    // ---- GEMM phase: wave wv handles output cols t0=2wv, t0+1
    const int wv = tid >> 6, lane = tid & 63;
    const int l16 = lane & 15, quad = lane >> 4;
    const int t0 = wv << 1;
    float4v acc0, acc1;
    {
        float b0v = bias[t0 * 16 + l16];
        float b1v = bias[(t0 + 1) * 16 + l16];
        float4v a0v = {b0v, b0v, b0v, b0v};
        float4v a1v = {b1v, b1v, b1v, b1v};
        acc0 = a0v; acc1 = a1v;
    }
    const unsigned short* bl = Bf + lane * 8;
    #pragma unroll
    for (int kc = 0; kc < 5; ++kc) {
        const unsigned short* Abase = (kc == 0) ? rootL : (aggL + (kc - 1) * 2048);
        #pragma unroll
        for (int ks = 0; ks < 4; ++ks) {
            const int C = ks * 4 + quad;
            const int p = C * 16 + (l16 ^ C);
            short8 af = *(const short8*)(Abase + p * 8);
            const unsigned short* bp = bl + (((kc * 4 + ks) * 8 + t0) << 9);
            short8 b0 = *(const short8*)(bp);
            short8 b1 = *(const short8*)(bp + 512);
            acc0 = __builtin_amdgcn_mfma_f32_16x16x32_bf16(af, b0, acc0, 0, 0, 0);
            acc1 = __builtin_amdgcn_mfma_f32_16x16x32_bf16(af, b1, acc1, 0, 0, 0);
        }
    }
    const int rowbase = tile * 16;
    #pragma unroll
    for (int rg = 0; rg < 4; ++rg) {
        int rr = rowbase + quad * 4 + rg;
        unsigned pk = (unsigned)f2bf(acc0[rg]) | ((unsigned)f2bf(acc1[rg]) << 16);
        *(unsigned*)(Cb + (size_t)rr * 128 + l16 * 8 + t0) = pk;
    }
    float s0 = 0.f, q0 = 0.f, s1 = 0.f, q1 = 0.f;
    #pragma unroll
    for (int rg = 0; rg < 4; ++rg) {
        float v0 = acc0[rg], v1 = acc1[rg];
        s0 += v0; q0 += v0 * v0; s1 += v1; q1 += v1 * v1;
    }
    s0 += __shfl_down(s0, 32, 64); q0 += __shfl_down(q0, 32, 64);
    s1 += __shfl_down(s1, 32, 64); q1 += __shfl_down(q1, 32, 64);
    s0 += __shfl_down(s0, 16, 64); q0 += __shfl_down(q0, 16, 64);
    s1 += __shfl_down(s1, 16, 64); q1 += __shfl_down(q1, 16, 64);
    if (lane < 16) {
        float* bnS = bnSums + ((tile & 7) << 8);
        unsafeAtomicAdd(bnS + t0 * 16 + l16, s0);
        unsafeAtomicAdd(bnS + 128 + t0 * 16 + l16, q0);
        unsafeAtomicAdd(bnS + (t0 + 1) * 16 + l16, s1);
        unsafeAtomicAdd(bnS + 128 + (t0 + 1) * 16 + l16, q1);
    }
}

// ---------------------------------------------------------------- layer-0 BN/PReLU/L2norm -> hbf (fin computed per block)

__global__ __launch_bounds__(256) void bn_apply_kernel(const unsigned short* __restrict__ Cb,
                                unsigned short* __restrict__ hbf,
                                const float* __restrict__ bnSums,
                                const float* __restrict__ gamma, const float* __restrict__ beta,
                                const float* __restrict__ prelu_a, int layer) {
    __shared__ float finS[256];
    const int tid = threadIdx.x;
    if (tid < 128) {
        float s = 0.f, q = 0.f;
        #pragma unroll
        for (int j = 0; j < 8; ++j) { s += bnSums[j * 256 + tid]; q += bnSums[j * 256 + 128 + tid]; }
        const float invn = 1.0f / (float)NN;
        float mu = s * invn;
        float var = q * invn - mu * mu; if (var < 0.f) var = 0.f;
        finS[tid] = mu;
        finS[128 + tid] = rsqrtf(var + 1e-5f);
    }
    __syncthreads();
    const int row = blockIdx.x * 16 + (tid >> 4);
    const int li = tid & 15;
    const int p8 = li << 3;
    const float a = prelu_a[layer];
    uint4 u = *(const uint4*)(Cb + (size_t)row * 128 + p8);
    float v[8];
    v[0] = __uint_as_float(u.x << 16); v[1] = __uint_as_float(u.x & 0xffff0000u);
    v[2] = __uint_as_float(u.y << 16); v[3] = __uint_as_float(u.y & 0xffff0000u);
    v[4] = __uint_as_float(u.z << 16); v[5] = __uint_as_float(u.z & 0xffff0000u);
    v[6] = __uint_as_float(u.w << 16); v[7] = __uint_as_float(u.w & 0xffff0000u);
    float t[8]; float ss = 0.f;
    #pragma unroll
    for (int j = 0; j < 8; ++j) {
        int cc = j * 16 + li;
        float tv = (v[j] - finS[cc]) * finS[128 + cc] * gamma[cc] + beta[cc];
        tv = (tv >= 0.f) ? tv : a * tv;
        t[j] = tv; ss += tv * tv;
    }
    ss += __shfl_xor(ss, 1, 64);
    ss += __shfl_xor(ss, 2, 64);
    ss += __shfl_xor(ss, 4, 64);
    ss += __shfl_xor(ss, 8, 64);
    const float scale = 1.0f / fmaxf(sqrtf(ss), 1e-12f);
    unsigned short o[8];
    #pragma unroll
    for (int j = 0; j < 8; ++j) o[j] = f2bf(t[j] * scale);
    *(uint4*)(hbf + (size_t)row * 128 + p8) = *(uint4*)o;
}

// ---------------------------------------------------------------- layer-1 BN/PReLU/L2norm + fused pooling (fin per block)

__global__ __launch_bounds__(256) void bn_apply_pool(const unsigned short* __restrict__ Cb,
                                const float* __restrict__ bnSums,
                                const float* __restrict__ gamma, const float* __restrict__ beta,
                                const float* __restrict__ prelu_a,
                                const int* __restrict__ batch,
                                float* __restrict__ g0) {
    __shared__ float P[16][128];
    __shared__ int gids[16];
    __shared__ float finS[256];
    const int tid = threadIdx.x;
    if (tid < 128) {
        float s = 0.f, q = 0.f;
        #pragma unroll
        for (int j = 0; j < 8; ++j) { s += bnSums[j * 256 + tid]; q += bnSums[j * 256 + 128 + tid]; }
        const float invn = 1.0f / (float)NN;
        float mu = s * invn;
        float var = q * invn - mu * mu; if (var < 0.f) var = 0.f;
        finS[tid] = mu;
        finS[128 + tid] = rsqrtf(var + 1e-5f);
    }
    const int r16 = tid >> 4;
    const int li = tid & 15;
    const int row = blockIdx.x * 16 + r16;
    const int p8 = li << 3;
    if (li == 0) gids[r16] = batch[row];
    __syncthreads();
    const float a = prelu_a[1];
    uint4 u = *(const uint4*)(Cb + (size_t)row * 128 + p8);
    float v[8];
    v[0] = __uint_as_float(u.x << 16); v[1] = __uint_as_float(u.x & 0xffff0000u);
    v[2] = __uint_as_float(u.y << 16); v[3] = __uint_as_float(u.y & 0xffff0000u);
    v[4] = __uint_as_float(u.z << 16); v[5] = __uint_as_float(u.z & 0xffff0000u);
    v[6] = __uint_as_float(u.w << 16); v[7] = __uint_as_float(u.w & 0xffff0000u);
    float t[8]; float ss = 0.f;
    #pragma unroll
    for (int j = 0; j < 8; ++j) {
        int cc = j * 16 + li;
        float tv = (v[j] - finS[cc]) * finS[128 + cc] * gamma[cc] + beta[cc];
        tv = (tv >= 0.f) ? tv : a * tv;
        t[j] = tv; ss += tv * tv;
    }
    ss += __shfl_xor(ss, 1, 64);
    ss += __shfl_xor(ss, 2, 64);
    ss += __shfl_xor(ss, 4, 64);
    ss += __shfl_xor(ss, 8, 64);
    const float scale = 1.0f / fmaxf(sqrtf(ss), 1e-12f);
    #pragma unroll
    for (int j = 0; j < 8; ++j) P[r16][p8 + j] = t[j] * scale;
    __syncthreads();
    if (tid < 128) {
        int cur = gids[0];
        float run = 0.f;
        #pragma unroll
        for (int rr = 0; rr < 16; ++rr) {
            int g = gids[rr];
            if (g != cur) {
                unsafeAtomicAdd(&g0[(size_t)cur * 128 + tid], run);
                run = 0.f; cur = g;
            }
            run += P[rr][tid];
        }
        unsafeAtomicAdd(&g0[(size_t)cur * 128 + tid], run);
    }
}

// ---------------------------------------------------------------- fused MLP: fc1 (applies 1/cnt) + fc2 + out

__global__ __launch_bounds__(256) void mlp_kernel(const float* __restrict__ g,
                                                  const float* __restrict__ w1,
                                                  const float* __restrict__ b1,
                                                  const int* __restrict__ batch,
                                                  const float* __restrict__ w2,
                                                  const float* __restrict__ b2,
                                                  const float* __restrict__ outw,
                                                  const float* __restrict__ outb,
                                                  float* __restrict__ out) {
    __shared__ float g1L[256];
    __shared__ int se[2];
    __shared__ float wsum[2];
    const int row = blockIdx.x;   // 512
    const int j = threadIdx.x;    // 256
    if (j < 2) se[j] = lower_bound_dev(batch, NN, row + j);
    __syncthreads();
    const int c = se[1] - se[0];
    const float invc = 1.0f / (float)(c > 0 ? c : 1);
    float acc = 0.f;
    #pragma unroll 8
    for (int k = 0; k < 128; ++k) {
        int lk = (k & 7) * 16 + (k >> 3);         // logical feature for mem pos k
        acc += g[row * 128 + k] * w1[lk * 256 + j];
    }
    g1L[j] = fmaxf(acc * invc + b1[j], 0.f);
    __syncthreads();
    if (j < 128) {
        float acc2 = b2[j];
        #pragma unroll 8
        for (int k = 0; k < 256; ++k) acc2 += g1L[k] * w2[k * 128 + j];
        float cc = fmaxf(acc2, 0.f) * outw[j];
        cc += __shfl_down(cc, 32, 64);
        cc += __shfl_down(cc, 16, 64);
        cc += __shfl_down(cc, 8, 64);
        cc += __shfl_down(cc, 4, 64);
        cc += __shfl_down(cc, 2, 64);
        cc += __shfl_down(cc, 1, 64);
        if ((j & 63) == 0) wsum[j >> 6] = cc;
    }
    __syncthreads();
    if (j == 0) out[row] = wsum[0] + wsum[1] + outb[0];
}

// ---------------------------------------------------------------- launcher

extern "C" void kernel_launch(void* const* d_in, const int* in_sizes, int n_in,
                              void* d_out, int out_size, void* d_ws, size_t ws_size,
                              hipStream_t stream) {
    const float* x      = (const float*)d_in[0];
    const int*   eidx   = (const int*)d_in[1];
    const int*   etype  = (const int*)d_in[2];
    const int*   batch  = (const int*)d_in[3];
    const float* emb    = (const float*)d_in[4];
    const float* Wrel   = (const float*)d_in[5];
    const float* Wroot  = (const float*)d_in[6];
    const float* cbias  = (const float*)d_in[7];
    const float* gamma  = (const float*)d_in[8];
    const float* beta   = (const float*)d_in[9];
    const float* prelua = (const float*)d_in[10];
    const float* fc1w   = (const float*)d_in[11];
    const float* fc1b   = (const float*)d_in[12];
    const float* fc2w   = (const float*)d_in[13];
    const float* fc2b   = (const float*)d_in[14];
    const float* outw   = (const float*)d_in[15];
    const float* outb   = (const float*)d_in[16];
    float* out = (float*)d_out;

    const int* src = eidx;
    const int* dst = eidx + NE;

    // workspace carve-up (aligned 256B)
    char* p = (char*)d_ws;
    auto alloc = [&](size_t bytes) { char* r = p; p += (bytes + 255) & ~(size_t)255; return r; };
    unsigned short* hbf   = (unsigned short*)alloc((size_t)NN * 128 * 2);  // 25.6 MB
    unsigned short* Cb    = (unsigned short*)alloc((size_t)NN * 128 * 2);  // 25.6 MB
    unsigned* partials = (unsigned*)alloc((size_t)NCH * BPC * CHW * 4);    // 16.8 MB
    int*   sortedSrc = (int*)alloc((size_t)NE * 4);                        // 6.4 MB
    int*   srcT      = (int*)alloc((size_t)NE * 4);                        // 6.4 MB
    int*   offs      = (int*)alloc((size_t)(NN + 1) * 4);
    int*   bsums     = (int*)alloc(1024);
    int*   ntype     = (int*)alloc((size_t)NN * 4);
    unsigned short* Bf1 = (unsigned short*)alloc((size_t)81920 * 2);
    unsigned short* B0f = (unsigned short*)alloc((size_t)12288 * 2);
    float* bnSums  = (float*)alloc(2048 * 4);
    float* bnSums1 = (float*)alloc(2048 * 4);
    float* g0      = (float*)alloc((size_t)NG * 128 * 4);

    const int NBLK = (NN + 1023) / 1024;   // 98

    // ---- weights + node types + zero inits (one kernel)
    build_weights<<<624 + (NN + 255) / 256, 256, 0, stream>>>(emb, Wroot, Wrel, x,
                                                              Bf1, B0f, ntype,
                                                              bnSums, bnSums1, g0);

    // ---- CSR build over dst (2 chunk passes; chunk-0 also packs srcT)
    hist_kernel<<<dim3(BPC, NCH), 1024, 0, stream>>>(dst, src, etype, ntype, srcT, partials);
    hr_scan1<<<NBLK, 256, 0, stream>>>(partials, offs, bsums, NN);
    scan23<<<NBLK, 256, 0, stream>>>(offs, bsums, NBLK, NN);
    place_kernel<<<dim3(BPC, NCH), 1024, 0, stream>>>(dst, srcT, offs, partials, sortedSrc);

    // ---- layer 0: fused histogram + GEMM, then BN/PReLU/L2norm
    gemm0_fused<<<(NN + 127) / 128, 256, 0, stream>>>(sortedSrc, offs, ntype, B0f,
                                                      cbias, Cb, bnSums, NN);
    bn_apply_kernel<<<NN / 16, 256, 0, stream>>>(Cb, hbf, bnSums, gamma, beta, prelua, 0);

    // ---- layer 1: fused gather + GEMM (pinned), then BN + fused pooling
    gather_gemm1<<<NN / 16, 256, 0, stream>>>(hbf, sortedSrc, offs, Bf1, cbias + 128, Cb, bnSums1);
    bn_apply_pool<<<NN / 16, 256, 0, stream>>>(Cb, bnSums1, gamma + 128, beta + 128,
                                               prelua, batch, g0);

    // ---- fused MLP
    mlp_kernel<<<NG, 256, 0, stream>>>(g0, fc1w, fc1b, batch, fc2w, fc2b, outw, outb, out);
}